// Round 1
// baseline (959.243 us; speedup 1.0000x reference)
//
#include <hip/hip_runtime.h>
#include <hip/hip_bf16.h>
#include <math.h>

// Mamba2 fused block, round 0: f32 VALU GEMMs, bf16 intermediates.
// Pipeline: k_proj -> k_conv416 / k_conv16 -> k_kv -> k_ynorm -> k_gemm_out.

#define BN 4
#define HH 128
#define WWID 128
#define LTOK (HH*WWID)          // 16384
#define NTOK (BN*LTOK)          // 65536
#define DMODEL 192
#define DINNER 384
#define NH 32
#define HD 12
#define DST 16
#define CONVD 416               // D_INNER + 2*16

typedef __hip_bfloat16 bf16;
typedef unsigned int uint32;
typedef unsigned short ushort16;

__device__ __forceinline__ float bflo(uint32 v){ return __uint_as_float((v & 0xffffu) << 16); }
__device__ __forceinline__ float bfhi(uint32 v){ return __uint_as_float(v & 0xffff0000u); }
__device__ __forceinline__ ushort16 f2bf(float f){
    __hip_bfloat16 h = __float2bfloat16(f);
    return *reinterpret_cast<const ushort16*>(&h);
}
__device__ __forceinline__ float softplusf(float x){
    return (x > 20.f) ? x : log1pf(expf(x));
}
__device__ __forceinline__ float siluf(float x){
    return x / (1.f + expf(-x));
}

// ---------------------------------------------------------------------------
// k_proj: zxbcdt = u @ W_in^T (832 ch) and cq_pre = t @ W_t_in[784:800]^T.
// 128 tokens x 128 ch tiles, 8x8 per thread, transposed LDS (As[k][m]).
// grid (512, 8): by 0..5 full Win tiles, by==6 Win rows 768..831, by==7 t-path.
// ---------------------------------------------------------------------------
__global__ __launch_bounds__(256) void k_proj(
    const float* __restrict__ u, const float* __restrict__ t,
    const float* __restrict__ Win, const float* __restrict__ Wtin,
    const float* __restrict__ dt_b, const float* __restrict__ A_log,
    bf16* __restrict__ z_bf, bf16* __restrict__ xbc_pre,
    float* __restrict__ cq_pre, float* __restrict__ dA)
{
    const int tid = threadIdx.x;
    const int m0 = blockIdx.x * 128;
    const int by = blockIdx.y;

    const float* Ap; const float* Wp; int nvalid, nbase;
    if (by < 6)      { Ap = u; Wp = Win  + by*128*DMODEL; nvalid = 128; nbase = by*128; }
    else if (by==6)  { Ap = u; Wp = Win  + 768*DMODEL;    nvalid = 64;  nbase = 768; }
    else             { Ap = t; Wp = Wtin + 784*DMODEL;    nvalid = 16;  nbase = 0; }

    __shared__ float As[16][132];
    __shared__ float Bs[16][132];

    float acc[8][8];
    #pragma unroll
    for (int i=0;i<8;++i)
        #pragma unroll
        for (int j=0;j<8;++j) acc[i][j]=0.f;

    const int tm = tid & 15;
    const int tn = tid >> 4;

    for (int k0 = 0; k0 < DMODEL; k0 += 16) {
        #pragma unroll
        for (int h2=0; h2<2; ++h2) {
            const int idx = tid + h2*256;
            const int row = idx >> 2;
            const int c4  = (idx & 3) * 4;
            const float4 av = *(const float4*)(Ap + (size_t)(m0+row)*DMODEL + k0 + c4);
            As[c4+0][row]=av.x; As[c4+1][row]=av.y; As[c4+2][row]=av.z; As[c4+3][row]=av.w;
            float4 bv = make_float4(0.f,0.f,0.f,0.f);
            if (row < nvalid) bv = *(const float4*)(Wp + (size_t)row*DMODEL + k0 + c4);
            Bs[c4+0][row]=bv.x; Bs[c4+1][row]=bv.y; Bs[c4+2][row]=bv.z; Bs[c4+3][row]=bv.w;
        }
        __syncthreads();
        #pragma unroll
        for (int k=0;k<16;++k) {
            float a[8], b[8];
            const float4 t0 = *(const float4*)&As[k][tm*8];
            const float4 t1 = *(const float4*)&As[k][tm*8+4];
            a[0]=t0.x;a[1]=t0.y;a[2]=t0.z;a[3]=t0.w;a[4]=t1.x;a[5]=t1.y;a[6]=t1.z;a[7]=t1.w;
            const float4 s0 = *(const float4*)&Bs[k][tn*8];
            const float4 s1 = *(const float4*)&Bs[k][tn*8+4];
            b[0]=s0.x;b[1]=s0.y;b[2]=s0.z;b[3]=s0.w;b[4]=s1.x;b[5]=s1.y;b[6]=s1.z;b[7]=s1.w;
            #pragma unroll
            for (int i=0;i<8;++i)
                #pragma unroll
                for (int j=0;j<8;++j) acc[i][j] = fmaf(a[i], b[j], acc[i][j]);
        }
        __syncthreads();
    }

    #pragma unroll
    for (int i=0;i<8;++i) {
        const int tok = m0 + tm*8 + i;
        #pragma unroll
        for (int j=0;j<8;++j) {
            const int nl = tn*8 + j;
            if (nl >= nvalid) continue;
            const float v = acc[i][j];
            if (by == 7) {
                cq_pre[(size_t)tok*DST + nl] = v;
            } else {
                const int n = nbase + nl;
                if (n < DINNER) {
                    z_bf[(size_t)tok*DINNER + n] = __float2bfloat16(v);
                } else if (n < DINNER + CONVD) {
                    xbc_pre[(size_t)tok*CONVD + (n - DINNER)] = __float2bfloat16(v);
                } else {
                    const int hh = n - (DINNER + CONVD);
                    const float dt = softplusf(v + dt_b[hh]);
                    dA[(size_t)tok*NH + hh] = dt * expf(A_log[hh]);
                }
            }
        }
    }
}

// ---------------------------------------------------------------------------
// k_conv416: depthwise 3x3 SAME conv + bias + SiLU over 416 channels (NHWC,
// bf16). 2 pixels per block, 2 channels per thread (dword loads/stores).
// ---------------------------------------------------------------------------
__global__ __launch_bounds__(448) void k_conv416(
    const bf16* __restrict__ in, const float* __restrict__ cw, const float* __restrict__ cb,
    bf16* __restrict__ out)
{
    const int tid = threadIdx.x;
    if (tid >= 416) return;
    const int pl = (tid >= 208) ? 1 : 0;
    const int c2 = tid - pl*208;
    const int c  = c2*2;
    const int pix = blockIdx.x*2 + pl;
    const int hw = pix & (LTOK-1);
    const int h = hw >> 7;
    const int w = hw & 127;
    const int bb = pix >> 14;

    float w0[9], w1[9];
    #pragma unroll
    for (int k=0;k<9;++k){ w0[k]=cw[c*9+k]; w1[k]=cw[(c+1)*9+k]; }
    float a0 = cb[c], a1 = cb[c+1];

    #pragma unroll
    for (int dh=-1; dh<=1; ++dh) {
        const int hh = h + dh;
        if ((unsigned)hh >= (unsigned)HH) continue;
        #pragma unroll
        for (int dw=-1; dw<=1; ++dw) {
            const int w2 = w + dw;
            if ((unsigned)w2 >= (unsigned)WWID) continue;
            const size_t off = ((size_t)((bb<<14) + (hh<<7) + w2))*CONVD + c;
            const uint32 v = *(const uint32*)((const ushort16*)in + off);
            const int wi = (dh+1)*3 + (dw+1);
            a0 = fmaf(bflo(v), w0[wi], a0);
            a1 = fmaf(bfhi(v), w1[wi], a1);
        }
    }
    const uint32 o = ((uint32)f2bf(siluf(a1)) << 16) | (uint32)f2bf(siluf(a0));
    *(uint32*)((ushort16*)out + (size_t)pix*CONVD + c) = o;
}

// ---------------------------------------------------------------------------
// k_conv16: same conv for the 16 Cq channels (conv channels 400..415), f32.
// ---------------------------------------------------------------------------
__global__ __launch_bounds__(256) void k_conv16(
    const float* __restrict__ in, const float* __restrict__ cw, const float* __restrict__ cb,
    float* __restrict__ out)
{
    const int idx = blockIdx.x*256 + threadIdx.x;   // NTOK*16
    const int cc = idx & 15;
    const int pix = idx >> 4;
    const int hw = pix & (LTOK-1);
    const int h = hw >> 7, w = hw & 127;
    const int bb = pix >> 14;
    const int c = 400 + cc;

    float wg[9];
    #pragma unroll
    for (int k=0;k<9;++k) wg[k] = cw[c*9+k];
    float a = cb[c];
    #pragma unroll
    for (int dh=-1; dh<=1; ++dh) {
        const int hh = h + dh;
        if ((unsigned)hh >= (unsigned)HH) continue;
        #pragma unroll
        for (int dw=-1; dw<=1; ++dw) {
            const int w2 = w + dw;
            if ((unsigned)w2 >= (unsigned)WWID) continue;
            a = fmaf(in[((size_t)((bb<<14)+(hh<<7)+w2))*16 + cc], wg[(dh+1)*3 + (dw+1)], a);
        }
    }
    out[(size_t)pix*16 + cc] = siluf(a);
}

// ---------------------------------------------------------------------------
// k_kv: KV[b,h,n,d] = sum_l Bk[b,l,n] * x[b,l,h*12+d] * dA[b,l,h].
// grid (64, B), 512 threads; thread (n = tid&15, head g = tid>>4) holds 12 d.
// Partial sums atomically added into kv (zeroed by memset).
// ---------------------------------------------------------------------------
__global__ __launch_bounds__(512) void k_kv(
    const bf16* __restrict__ xbc_post, const float* __restrict__ dA, float* __restrict__ kv)
{
    const int tid = threadIdx.x;
    const int b = blockIdx.y;
    const int n = tid & 15;
    const int g = tid >> 4;    // head
    __shared__ float vs[DINNER];
    __shared__ float bks[DST];
    float acc[12];
    #pragma unroll
    for (int j=0;j<12;++j) acc[j]=0.f;
    const int l0 = b*LTOK + blockIdx.x*256;
    const int myh = tid / 6;   // head for staging pair (tid<192)

    for (int it=0; it<256; ++it) {
        const int l = l0 + it;
        const size_t base = (size_t)l*CONVD;
        if (tid < 192) {
            const uint32 v = *(const uint32*)((const ushort16*)xbc_post + base + tid*2);
            const float da = dA[(size_t)l*NH + myh];
            vs[tid*2]   = bflo(v) * da;
            vs[tid*2+1] = bfhi(v) * da;
        } else if (tid < 200) {
            const int i2 = tid - 192;
            const uint32 v = *(const uint32*)((const ushort16*)xbc_post + base + DINNER + i2*2);
            bks[i2*2]   = bflo(v);
            bks[i2*2+1] = bfhi(v);
        }
        __syncthreads();
        const float bkv = bks[n];
        #pragma unroll
        for (int j2=0;j2<6;++j2) {
            const float2 vv = *(const float2*)&vs[g*12 + j2*2];
            acc[j2*2]   = fmaf(bkv, vv.x, acc[j2*2]);
            acc[j2*2+1] = fmaf(bkv, vv.y, acc[j2*2+1]);
        }
        __syncthreads();
    }
    #pragma unroll
    for (int j=0;j<12;++j) atomicAdd(&kv[((size_t)(b*NH + g)*DST + n)*HD + j], acc[j]);
}

// ---------------------------------------------------------------------------
// k_ynorm: y = Cq @ KV + V*D, LayerNorm(384), gate by z -> yz (bf16).
// 16 tokens per block. kvs in LDS transposed to [n][hd] (conflict-free reads).
// ---------------------------------------------------------------------------
__global__ __launch_bounds__(256) void k_ynorm(
    const bf16* __restrict__ xbc_post, const float* __restrict__ cq_post,
    const bf16* __restrict__ z_bf, const float* __restrict__ kv,
    const float* __restrict__ Dv, const float* __restrict__ ln_g, const float* __restrict__ ln_b,
    bf16* __restrict__ yz)
{
    __shared__ float kvs[NH*DST*HD];   // 6144, layout [n][hd]
    __shared__ float ys[16][386];
    __shared__ float cqs[16][16];
    const int tid = threadIdx.x;
    const int token0 = blockIdx.x * 16;
    const int b = token0 >> 14;

    for (int i = tid; i < NH*DST*HD; i += 256) {
        const int n = i / DINNER;
        const int hd = i - n*DINNER;
        const int h = hd / HD;
        const int d = hd - h*HD;
        kvs[i] = kv[((size_t)(b*NH + h)*DST + n)*HD + d];
    }
    {
        const int tt = tid >> 4, n2 = tid & 15;
        cqs[tt][n2] = cq_post[(size_t)(token0+tt)*DST + n2];
    }
    __syncthreads();

    #pragma unroll
    for (int jj=0; jj<12; ++jj) {
        const int flat = jj*256 + tid;     // 0..3071 (pairs)
        const int tt = flat / 192;
        const int p  = flat - tt*192;
        const int hd = p*2;
        const int h = hd / HD;
        const int l = token0 + tt;
        const uint32 v = *(const uint32*)((const ushort16*)xbc_post + (size_t)l*CONVD + hd);
        const float dv = Dv[h];
        float a0 = bflo(v) * dv;
        float a1 = bfhi(v) * dv;
        #pragma unroll
        for (int n=0;n<16;++n) {
            const float c = cqs[tt][n];
            const float2 kk = *(const float2*)&kvs[n*DINNER + hd];
            a0 = fmaf(c, kk.x, a0);
            a1 = fmaf(c, kk.y, a1);
        }
        *(float2*)&ys[tt][hd] = make_float2(a0, a1);
    }
    __syncthreads();

    const int wave = tid >> 6, lane = tid & 63;
    #pragma unroll
    for (int i=0;i<4;++i) {
        const int tt = wave*4 + i;
        const int l = token0 + tt;
        float v[6]; float s=0.f, s2=0.f;
        #pragma unroll
        for (int k=0;k<6;++k){ const float x = ys[tt][k*64+lane]; v[k]=x; s+=x; s2=fmaf(x,x,s2); }
        #pragma unroll
        for (int off=32; off>0; off>>=1){ s += __shfl_xor(s,off,64); s2 += __shfl_xor(s2,off,64); }
        const float mu = s*(1.f/384.f);
        const float var = s2*(1.f/384.f) - mu*mu;
        const float rs = rsqrtf(var + 1e-5f);
        #pragma unroll
        for (int k=0;k<6;++k){
            const int idx = k*64+lane;
            const float yn = (v[k]-mu)*rs*ln_g[idx] + ln_b[idx];
            const uint32 zb = (uint32)(*((const ushort16*)z_bf + (size_t)l*DINNER + idx));
            const float zv = __uint_as_float(zb << 16);
            yz[(size_t)l*DINNER + idx] = __float2bfloat16(yn*zv);
        }
    }
}

// ---------------------------------------------------------------------------
// k_gemm_out: out[l][m] = sum_k yz[l][k] * W_out[m][k].  128x128 tiles,
// 8x8 per thread; A staged from bf16. grid (512, 2) (second n-tile: 64 valid).
// ---------------------------------------------------------------------------
__global__ __launch_bounds__(256) void k_gemm_out(
    const bf16* __restrict__ yz, const float* __restrict__ Wout, float* __restrict__ out)
{
    const int tid = threadIdx.x;
    const int m0 = blockIdx.x * 128;
    const int n0 = blockIdx.y * 128;
    const int nvalid = (n0 == 0) ? 128 : 64;

    __shared__ float As[16][132];
    __shared__ float Bs[16][132];

    float acc[8][8];
    #pragma unroll
    for (int i=0;i<8;++i)
        #pragma unroll
        for (int j=0;j<8;++j) acc[i][j]=0.f;

    const int tm = tid & 15;
    const int tn = tid >> 4;

    for (int k0 = 0; k0 < DINNER; k0 += 16) {
        {
            const int row = tid >> 1, k8 = (tid & 1)*8;
            const uint4 av = *(const uint4*)((const ushort16*)yz + (size_t)(m0+row)*DINNER + k0 + k8);
            As[k8+0][row] = bflo(av.x); As[k8+1][row] = bfhi(av.x);
            As[k8+2][row] = bflo(av.y); As[k8+3][row] = bfhi(av.y);
            As[k8+4][row] = bflo(av.z); As[k8+5][row] = bfhi(av.z);
            As[k8+6][row] = bflo(av.w); As[k8+7][row] = bfhi(av.w);
        }
        #pragma unroll
        for (int h2=0; h2<2; ++h2) {
            const int i = tid + h2*256;
            const int row = i >> 2, c4 = (i & 3)*4;
            float4 bv = make_float4(0.f,0.f,0.f,0.f);
            if (row < nvalid) bv = *(const float4*)(Wout + (size_t)(n0+row)*DINNER + k0 + c4);
            Bs[c4+0][row]=bv.x; Bs[c4+1][row]=bv.y; Bs[c4+2][row]=bv.z; Bs[c4+3][row]=bv.w;
        }
        __syncthreads();
        #pragma unroll
        for (int k=0;k<16;++k) {
            float a[8], b[8];
            const float4 t0 = *(const float4*)&As[k][tm*8];
            const float4 t1 = *(const float4*)&As[k][tm*8+4];
            a[0]=t0.x;a[1]=t0.y;a[2]=t0.z;a[3]=t0.w;a[4]=t1.x;a[5]=t1.y;a[6]=t1.z;a[7]=t1.w;
            const float4 s0 = *(const float4*)&Bs[k][tn*8];
            const float4 s1 = *(const float4*)&Bs[k][tn*8+4];
            b[0]=s0.x;b[1]=s0.y;b[2]=s0.z;b[3]=s0.w;b[4]=s1.x;b[5]=s1.y;b[6]=s1.z;b[7]=s1.w;
            #pragma unroll
            for (int i=0;i<8;++i)
                #pragma unroll
                for (int j=0;j<8;++j) acc[i][j] = fmaf(a[i], b[j], acc[i][j]);
        }
        __syncthreads();
    }

    #pragma unroll
    for (int i=0;i<8;++i) {
        const int tok = m0 + tm*8 + i;
        #pragma unroll
        for (int j=0;j<8;++j) {
            const int nl = tn*8 + j;
            if (nl < nvalid) out[(size_t)tok*DMODEL + n0 + nl] = acc[i][j];
        }
    }
}

// ---------------------------------------------------------------------------
extern "C" void kernel_launch(void* const* d_in, const int* in_sizes, int n_in,
                              void* d_out, int out_size, void* d_ws, size_t ws_size,
                              hipStream_t stream)
{
    const float* u      = (const float*)d_in[0];
    const float* t      = (const float*)d_in[1];
    const float* Win    = (const float*)d_in[2];
    const float* Wtin   = (const float*)d_in[3];
    const float* conv_w = (const float*)d_in[4];
    const float* conv_b = (const float*)d_in[5];
    const float* dt_b   = (const float*)d_in[6];
    const float* A_log  = (const float*)d_in[7];
    const float* Dv     = (const float*)d_in[8];
    const float* ln_g   = (const float*)d_in[9];
    const float* ln_bt  = (const float*)d_in[10];
    const float* W_out  = (const float*)d_in[11];
    float* out = (float*)d_out;

    char* p = (char*)d_ws;
    bf16* z_bf     = (bf16*)p;  p += (size_t)NTOK*DINNER*2;   // 50.3 MB
    bf16* xbc_pre  = (bf16*)p;  p += (size_t)NTOK*CONVD*2;    // 54.5 MB
    bf16* xbc_post = (bf16*)p;  p += (size_t)NTOK*CONVD*2;    // 54.5 MB
    float* cq_pre  = (float*)p; p += (size_t)NTOK*DST*4;      //  4.2 MB
    float* cq_post = (float*)p; p += (size_t)NTOK*DST*4;      //  4.2 MB
    float* dA      = (float*)p; p += (size_t)NTOK*NH*4;       //  8.4 MB
    bf16* yz       = (bf16*)p;  p += (size_t)NTOK*DINNER*2;   // 50.3 MB
    float* kv      = (float*)p; p += (size_t)BN*NH*DST*HD*4;  // 98 KB
    // total ~216.2 MB

    hipMemsetAsync(kv, 0, (size_t)BN*NH*DST*HD*4, stream);
    k_proj<<<dim3(512, 8), 256, 0, stream>>>(u, t, Win, Wtin, dt_b, A_log,
                                             z_bf, xbc_pre, cq_pre, dA);
    k_conv416<<<NTOK/2, 448, 0, stream>>>(xbc_pre, conv_w, conv_b, xbc_post);
    k_conv16<<<NTOK*16/256, 256, 0, stream>>>(cq_pre, conv_w, conv_b, cq_post);
    k_kv<<<dim3(64, BN), 512, 0, stream>>>(xbc_post, dA, kv);
    k_ynorm<<<NTOK/16, 256, 0, stream>>>(xbc_post, cq_post, z_bf, kv,
                                         Dv, ln_g, ln_bt, yz);
    k_gemm_out<<<dim3(512, 2), 256, 0, stream>>>(yz, W_out, out);
}

// Round 2
// 527.070 us; speedup vs baseline: 1.8200x; 1.8200x over previous
//
#include <hip/hip_runtime.h>
#include <hip/hip_bf16.h>
#include <math.h>

// Mamba2 fused block, round 2: bf16 MFMA GEMMs (in-proj + out-proj),
// split t-path (only 16 surviving channels), rest unchanged.

#define BN 4
#define HH 128
#define WWID 128
#define LTOK (HH*WWID)          // 16384
#define NTOK (BN*LTOK)          // 65536
#define DMODEL 192
#define DINNER 384
#define NH 32
#define HD 12
#define DST 16
#define CONVD 416               // D_INNER + 2*16

typedef __hip_bfloat16 bf16;
typedef unsigned int uint32;
typedef unsigned short ushort16;
typedef __attribute__((ext_vector_type(8))) short bf16x8;
typedef __attribute__((ext_vector_type(4))) float f32x4;

__device__ __forceinline__ float bflo(uint32 v){ return __uint_as_float((v & 0xffffu) << 16); }
__device__ __forceinline__ float bfhi(uint32 v){ return __uint_as_float(v & 0xffff0000u); }
__device__ __forceinline__ ushort16 f2bf(float f){
    __hip_bfloat16 h = __float2bfloat16(f);
    return *reinterpret_cast<const ushort16*>(&h);
}
__device__ __forceinline__ float softplusf(float x){
    return (x > 20.f) ? x : log1pf(expf(x));
}
__device__ __forceinline__ float siluf(float x){
    return x / (1.f + expf(-x));
}

union BFPK { short s[8]; bf16x8 v; };

// ---------------------------------------------------------------------------
// k_prep: convert Win (832x192) and Wout (192x384) to bf16.
// ---------------------------------------------------------------------------
__global__ __launch_bounds__(256) void k_prep(
    const float* __restrict__ Win, const float* __restrict__ Wout,
    bf16* __restrict__ Winbf, bf16* __restrict__ Woutbf)
{
    const int i = blockIdx.x*256 + threadIdx.x;
    if (i < 832*DMODEL)   Winbf[i]  = __float2bfloat16(Win[i]);
    if (i < DMODEL*DINNER) Woutbf[i] = __float2bfloat16(Wout[i]);
}

// ---------------------------------------------------------------------------
// k_proj_mfma: zxbcdt = u @ Win^T via 16x16x32 bf16 MFMA.
// Block: 128 tokens, full output N=832 (7 tiles of 128). A tile (f32->bf16)
// staged once in LDS [128][200] (pad -> 2-way conflict, free). B chunks
// [128][40] double-buffered, BK=32.  4 waves, each 64x64 per N-tile.
// ---------------------------------------------------------------------------
__global__ __launch_bounds__(256) void k_proj_mfma(
    const float* __restrict__ u, const bf16* __restrict__ Wbf,
    const float* __restrict__ dt_b, const float* __restrict__ A_log,
    bf16* __restrict__ z_bf, bf16* __restrict__ xbc_pre, float* __restrict__ dA)
{
    __shared__ __align__(16) short As[128*200];
    __shared__ __align__(16) short Bs[2][128*40];

    const int tid = threadIdx.x;
    const int m0 = blockIdx.x * 128;
    const int wid = tid >> 6, lane = tid & 63;
    const int wm = wid >> 1, wn = wid & 1;
    const int fr = lane & 15, fq = lane >> 4;

    // ---- stage A: 128x192 f32 -> bf16 LDS, 2 threads/row ----
    {
        const int row = tid >> 1, half = tid & 1;
        const float* src = u + (size_t)(m0 + row)*DMODEL + half*96;
        short* dst = &As[row*200 + half*96];
        #pragma unroll
        for (int i = 0; i < 12; ++i) {
            const float4 a0 = *(const float4*)(src + i*8);
            const float4 a1 = *(const float4*)(src + i*8 + 4);
            BFPK pk;
            pk.s[0]=(short)f2bf(a0.x); pk.s[1]=(short)f2bf(a0.y);
            pk.s[2]=(short)f2bf(a0.z); pk.s[3]=(short)f2bf(a0.w);
            pk.s[4]=(short)f2bf(a1.x); pk.s[5]=(short)f2bf(a1.y);
            pk.s[6]=(short)f2bf(a1.z); pk.s[7]=(short)f2bf(a1.w);
            *(bf16x8*)(dst + i*8) = pk.v;
        }
    }

    // ---- B chunk stager: Win rows [nt*128, nt*128+128), k [ks*32, ks*32+32) ----
    const int brow = tid >> 1, bhalf = tid & 1;
    auto stageB = [&](int nt, int ks, int buf) {
        const int ch = nt*128 + brow;
        uint4 v0 = make_uint4(0,0,0,0), v1 = make_uint4(0,0,0,0);
        if (ch < 832) {
            const short* g = (const short*)Wbf + (size_t)ch*DMODEL + ks*32 + bhalf*16;
            v0 = *(const uint4*)g;
            v1 = *(const uint4*)(g + 8);
        }
        short* d = &Bs[buf][brow*40 + bhalf*16];
        *(uint4*)d = v0;
        *(uint4*)(d + 8) = v1;
    };

    stageB(0, 0, 0);
    __syncthreads();

    const short* Ab = &As[(wm*64 + fr)*200 + fq*8];
    const int boff = (wn*64 + fr)*40 + fq*8;

    for (int nt = 0; nt < 7; ++nt) {
        f32x4 acc[4][4];
        #pragma unroll
        for (int mi=0;mi<4;++mi)
            #pragma unroll
            for (int ni=0;ni<4;++ni) acc[mi][ni] = (f32x4){0.f,0.f,0.f,0.f};

        #pragma unroll
        for (int ks = 0; ks < 6; ++ks) {
            const int cur = ks & 1;
            if (ks < 5)          stageB(nt,   ks+1, cur^1);
            else if (nt < 6)     stageB(nt+1, 0,    cur^1);

            bf16x8 a[4], b[4];
            #pragma unroll
            for (int mi=0;mi<4;++mi) a[mi] = *(const bf16x8*)(Ab + mi*3200 + ks*32);
            #pragma unroll
            for (int ni=0;ni<4;++ni) b[ni] = *(const bf16x8*)(&Bs[cur][boff + ni*640]);
            #pragma unroll
            for (int mi=0;mi<4;++mi)
                #pragma unroll
                for (int ni=0;ni<4;++ni)
                    acc[mi][ni] = __builtin_amdgcn_mfma_f32_16x16x32_bf16(a[mi], b[ni], acc[mi][ni], 0, 0, 0);
            __syncthreads();
        }

        // epilogue for this N-tile (acc in regs only, no LDS hazard)
        #pragma unroll
        for (int ni=0;ni<4;++ni) {
            const int n = nt*128 + wn*64 + ni*16 + fr;
            #pragma unroll
            for (int mi=0;mi<4;++mi) {
                #pragma unroll
                for (int j=0;j<4;++j) {
                    const int tok = m0 + wm*64 + mi*16 + fq*4 + j;
                    const float v = acc[mi][ni][j];
                    if (n < DINNER) {
                        z_bf[(size_t)tok*DINNER + n] = __float2bfloat16(v);
                    } else if (n < DINNER + CONVD) {
                        xbc_pre[(size_t)tok*CONVD + (n - DINNER)] = __float2bfloat16(v);
                    } else if (n < 832) {
                        const int hh = n - (DINNER + CONVD);
                        const float dt = softplusf(v + dt_b[hh]);
                        dA[(size_t)tok*NH + hh] = dt * expf(A_log[hh]);
                    }
                }
            }
        }
    }
}

// ---------------------------------------------------------------------------
// k_tproj: cq_pre[tok][n] = t[tok] . Wtin[784+n], n=0..15. 16 tokens/block.
// ---------------------------------------------------------------------------
__global__ __launch_bounds__(256) void k_tproj(
    const float* __restrict__ t, const float* __restrict__ Wtin, float* __restrict__ cq_pre)
{
    __shared__ float ts[16][196];
    __shared__ float ws[16][196];
    const int tid = threadIdx.x;
    const int tok0 = blockIdx.x * 16;
    #pragma unroll
    for (int i = 0; i < 3; ++i) {
        const int flat = tid + 256*i;          // 0..767
        const int row = flat / 48, c = (flat % 48)*4;
        *(float4*)&ts[row][c] = *(const float4*)(t    + (size_t)(tok0+row)*DMODEL + c);
        *(float4*)&ws[row][c] = *(const float4*)(Wtin + (size_t)(784+row)*DMODEL + c);
    }
    __syncthreads();
    const int tt = tid >> 4, n = tid & 15;
    float s0=0.f,s1=0.f,s2=0.f,s3=0.f;
    #pragma unroll 4
    for (int k = 0; k < DMODEL; k += 4) {
        s0 = fmaf(ts[tt][k+0], ws[n][k+0], s0);
        s1 = fmaf(ts[tt][k+1], ws[n][k+1], s1);
        s2 = fmaf(ts[tt][k+2], ws[n][k+2], s2);
        s3 = fmaf(ts[tt][k+3], ws[n][k+3], s3);
    }
    cq_pre[(size_t)(tok0+tt)*DST + n] = (s0+s1)+(s2+s3);
}

// ---------------------------------------------------------------------------
// k_conv416: depthwise 3x3 SAME conv + bias + SiLU over 416 channels (NHWC,
// bf16). 2 pixels per block, 2 channels per thread (dword loads/stores).
// ---------------------------------------------------------------------------
__global__ __launch_bounds__(448) void k_conv416(
    const bf16* __restrict__ in, const float* __restrict__ cw, const float* __restrict__ cb,
    bf16* __restrict__ out)
{
    const int tid = threadIdx.x;
    if (tid >= 416) return;
    const int pl = (tid >= 208) ? 1 : 0;
    const int c2 = tid - pl*208;
    const int c  = c2*2;
    const int pix = blockIdx.x*2 + pl;
    const int hw = pix & (LTOK-1);
    const int h = hw >> 7;
    const int w = hw & 127;
    const int bb = pix >> 14;

    float w0[9], w1[9];
    #pragma unroll
    for (int k=0;k<9;++k){ w0[k]=cw[c*9+k]; w1[k]=cw[(c+1)*9+k]; }
    float a0 = cb[c], a1 = cb[c+1];

    #pragma unroll
    for (int dh=-1; dh<=1; ++dh) {
        const int hh = h + dh;
        if ((unsigned)hh >= (unsigned)HH) continue;
        #pragma unroll
        for (int dw=-1; dw<=1; ++dw) {
            const int w2 = w + dw;
            if ((unsigned)w2 >= (unsigned)WWID) continue;
            const size_t off = ((size_t)((bb<<14) + (hh<<7) + w2))*CONVD + c;
            const uint32 v = *(const uint32*)((const ushort16*)in + off);
            const int wi = (dh+1)*3 + (dw+1);
            a0 = fmaf(bflo(v), w0[wi], a0);
            a1 = fmaf(bfhi(v), w1[wi], a1);
        }
    }
    const uint32 o = ((uint32)f2bf(siluf(a1)) << 16) | (uint32)f2bf(siluf(a0));
    *(uint32*)((ushort16*)out + (size_t)pix*CONVD + c) = o;
}

// ---------------------------------------------------------------------------
// k_conv16: same conv for the 16 Cq channels (conv channels 400..415), f32.
// ---------------------------------------------------------------------------
__global__ __launch_bounds__(256) void k_conv16(
    const float* __restrict__ in, const float* __restrict__ cw, const float* __restrict__ cb,
    float* __restrict__ out)
{
    const int idx = blockIdx.x*256 + threadIdx.x;   // NTOK*16
    const int cc = idx & 15;
    const int pix = idx >> 4;
    const int hw = pix & (LTOK-1);
    const int h = hw >> 7, w = hw & 127;
    const int bb = pix >> 14;
    const int c = 400 + cc;

    float wg[9];
    #pragma unroll
    for (int k=0;k<9;++k) wg[k] = cw[c*9+k];
    float a = cb[c];
    #pragma unroll
    for (int dh=-1; dh<=1; ++dh) {
        const int hh = h + dh;
        if ((unsigned)hh >= (unsigned)HH) continue;
        #pragma unroll
        for (int dw=-1; dw<=1; ++dw) {
            const int w2 = w + dw;
            if ((unsigned)w2 >= (unsigned)WWID) continue;
            a = fmaf(in[((size_t)((bb<<14)+(hh<<7)+w2))*16 + cc], wg[(dh+1)*3 + (dw+1)], a);
        }
    }
    out[(size_t)pix*16 + cc] = siluf(a);
}

// ---------------------------------------------------------------------------
// k_kv: KV[b,h,n,d] = sum_l Bk[b,l,n] * x[b,l,h*12+d] * dA[b,l,h].
// ---------------------------------------------------------------------------
__global__ __launch_bounds__(512) void k_kv(
    const bf16* __restrict__ xbc_post, const float* __restrict__ dA, float* __restrict__ kv)
{
    const int tid = threadIdx.x;
    const int b = blockIdx.y;
    const int n = tid & 15;
    const int g = tid >> 4;    // head
    __shared__ float vs[DINNER];
    __shared__ float bks[DST];
    float acc[12];
    #pragma unroll
    for (int j=0;j<12;++j) acc[j]=0.f;
    const int l0 = b*LTOK + blockIdx.x*256;
    const int myh = tid / 6;   // head for staging pair (tid<192)

    for (int it=0; it<256; ++it) {
        const int l = l0 + it;
        const size_t base = (size_t)l*CONVD;
        if (tid < 192) {
            const uint32 v = *(const uint32*)((const ushort16*)xbc_post + base + tid*2);
            const float da = dA[(size_t)l*NH + myh];
            vs[tid*2]   = bflo(v) * da;
            vs[tid*2+1] = bfhi(v) * da;
        } else if (tid < 200) {
            const int i2 = tid - 192;
            const uint32 v = *(const uint32*)((const ushort16*)xbc_post + base + DINNER + i2*2);
            bks[i2*2]   = bflo(v);
            bks[i2*2+1] = bfhi(v);
        }
        __syncthreads();
        const float bkv = bks[n];
        #pragma unroll
        for (int j2=0;j2<6;++j2) {
            const float2 vv = *(const float2*)&vs[g*12 + j2*2];
            acc[j2*2]   = fmaf(bkv, vv.x, acc[j2*2]);
            acc[j2*2+1] = fmaf(bkv, vv.y, acc[j2*2+1]);
        }
        __syncthreads();
    }
    #pragma unroll
    for (int j=0;j<12;++j) atomicAdd(&kv[((size_t)(b*NH + g)*DST + n)*HD + j], acc[j]);
}

// ---------------------------------------------------------------------------
// k_ynorm: y = Cq @ KV + V*D, LayerNorm(384), gate by z -> yz (bf16).
// ---------------------------------------------------------------------------
__global__ __launch_bounds__(256) void k_ynorm(
    const bf16* __restrict__ xbc_post, const float* __restrict__ cq_post,
    const bf16* __restrict__ z_bf, const float* __restrict__ kv,
    const float* __restrict__ Dv, const float* __restrict__ ln_g, const float* __restrict__ ln_b,
    bf16* __restrict__ yz)
{
    __shared__ float kvs[NH*DST*HD];   // 6144, layout [n][hd]
    __shared__ float ys[16][386];
    __shared__ float cqs[16][16];
    const int tid = threadIdx.x;
    const int token0 = blockIdx.x * 16;
    const int b = token0 >> 14;

    for (int i = tid; i < NH*DST*HD; i += 256) {
        const int n = i / DINNER;
        const int hd = i - n*DINNER;
        const int h = hd / HD;
        const int d = hd - h*HD;
        kvs[i] = kv[((size_t)(b*NH + h)*DST + n)*HD + d];
    }
    {
        const int tt = tid >> 4, n2 = tid & 15;
        cqs[tt][n2] = cq_post[(size_t)(token0+tt)*DST + n2];
    }
    __syncthreads();

    #pragma unroll
    for (int jj=0; jj<12; ++jj) {
        const int flat = jj*256 + tid;     // 0..3071 (pairs)
        const int tt = flat / 192;
        const int p  = flat - tt*192;
        const int hd = p*2;
        const int h = hd / HD;
        const int l = token0 + tt;
        const uint32 v = *(const uint32*)((const ushort16*)xbc_post + (size_t)l*CONVD + hd);
        const float dv = Dv[h];
        float a0 = bflo(v) * dv;
        float a1 = bfhi(v) * dv;
        #pragma unroll
        for (int n=0;n<16;++n) {
            const float c = cqs[tt][n];
            const float2 kk = *(const float2*)&kvs[n*DINNER + hd];
            a0 = fmaf(c, kk.x, a0);
            a1 = fmaf(c, kk.y, a1);
        }
        *(float2*)&ys[tt][hd] = make_float2(a0, a1);
    }
    __syncthreads();

    const int wave = tid >> 6, lane = tid & 63;
    #pragma unroll
    for (int i=0;i<4;++i) {
        const int tt = wave*4 + i;
        const int l = token0 + tt;
        float v[6]; float s=0.f, s2=0.f;
        #pragma unroll
        for (int k=0;k<6;++k){ const float x = ys[tt][k*64+lane]; v[k]=x; s+=x; s2=fmaf(x,x,s2); }
        #pragma unroll
        for (int off=32; off>0; off>>=1){ s += __shfl_xor(s,off,64); s2 += __shfl_xor(s2,off,64); }
        const float mu = s*(1.f/384.f);
        const float var = s2*(1.f/384.f) - mu*mu;
        const float rs = rsqrtf(var + 1e-5f);
        #pragma unroll
        for (int k=0;k<6;++k){
            const int idx = k*64+lane;
            const float yn = (v[k]-mu)*rs*ln_g[idx] + ln_b[idx];
            const uint32 zb = (uint32)(*((const ushort16*)z_bf + (size_t)l*DINNER + idx));
            const float zv = __uint_as_float(zb << 16);
            yz[(size_t)l*DINNER + idx] = __float2bfloat16(yn*zv);
        }
    }
}

// ---------------------------------------------------------------------------
// k_out_mfma: out = yz @ Wout^T via MFMA. BM=128, BN=192 (all N), BK=32
// double-buffered. 4 waves, each 64x96 (acc 4x6).
// ---------------------------------------------------------------------------
__global__ __launch_bounds__(256) void k_out_mfma(
    const bf16* __restrict__ yz, const bf16* __restrict__ Wbf, float* __restrict__ out)
{
    __shared__ __align__(16) short As[2][128*40];
    __shared__ __align__(16) short Bs[2][192*40];

    const int tid = threadIdx.x;
    const int m0 = blockIdx.x * 128;
    const int wid = tid >> 6, lane = tid & 63;
    const int wm = wid >> 1, wn = wid & 1;
    const int fr = lane & 15, fq = lane >> 4;

    const int arow = tid >> 1, ahalf = tid & 1;
    auto stageA = [&](int ks, int buf) {
        const short* g = (const short*)yz + (size_t)(m0 + arow)*DINNER + ks*32 + ahalf*16;
        const uint4 v0 = *(const uint4*)g;
        const uint4 v1 = *(const uint4*)(g + 8);
        short* d = &As[buf][arow*40 + ahalf*16];
        *(uint4*)d = v0;
        *(uint4*)(d + 8) = v1;
    };
    auto stageB = [&](int ks, int buf) {
        #pragma unroll
        for (int i = 0; i < 3; ++i) {
            const int flat = tid + 256*i;      // 0..767
            const int row = flat >> 2, q = flat & 3;
            const uint4 v = *(const uint4*)((const short*)Wbf + (size_t)row*DINNER + ks*32 + q*8);
            *(uint4*)&Bs[buf][row*40 + q*8] = v;
        }
    };

    f32x4 acc[4][6];
    #pragma unroll
    for (int mi=0;mi<4;++mi)
        #pragma unroll
        for (int ni=0;ni<6;++ni) acc[mi][ni] = (f32x4){0.f,0.f,0.f,0.f};

    stageA(0, 0); stageB(0, 0);
    __syncthreads();

    const int aoff = (wm*64 + fr)*40 + fq*8;
    const int boff = (wn*96 + fr)*40 + fq*8;

    #pragma unroll
    for (int ks = 0; ks < 12; ++ks) {
        const int cur = ks & 1;
        if (ks < 11) { stageA(ks+1, cur^1); stageB(ks+1, cur^1); }
        bf16x8 a[4], b[6];
        #pragma unroll
        for (int mi=0;mi<4;++mi) a[mi] = *(const bf16x8*)(&As[cur][aoff + mi*640]);
        #pragma unroll
        for (int ni=0;ni<6;++ni) b[ni] = *(const bf16x8*)(&Bs[cur][boff + ni*640]);
        #pragma unroll
        for (int mi=0;mi<4;++mi)
            #pragma unroll
            for (int ni=0;ni<6;++ni)
                acc[mi][ni] = __builtin_amdgcn_mfma_f32_16x16x32_bf16(a[mi], b[ni], acc[mi][ni], 0, 0, 0);
        __syncthreads();
    }

    #pragma unroll
    for (int mi=0;mi<4;++mi) {
        #pragma unroll
        for (int j=0;j<4;++j) {
            const int tok = m0 + wm*64 + mi*16 + fq*4 + j;
            #pragma unroll
            for (int ni=0;ni<6;++ni) {
                const int n = wn*96 + ni*16 + fr;
                out[(size_t)tok*DMODEL + n] = acc[mi][ni][j];
            }
        }
    }
}

// ---------------------------------------------------------------------------
extern "C" void kernel_launch(void* const* d_in, const int* in_sizes, int n_in,
                              void* d_out, int out_size, void* d_ws, size_t ws_size,
                              hipStream_t stream)
{
    const float* u      = (const float*)d_in[0];
    const float* t      = (const float*)d_in[1];
    const float* Win    = (const float*)d_in[2];
    const float* Wtin   = (const float*)d_in[3];
    const float* conv_w = (const float*)d_in[4];
    const float* conv_b = (const float*)d_in[5];
    const float* dt_b   = (const float*)d_in[6];
    const float* A_log  = (const float*)d_in[7];
    const float* Dv     = (const float*)d_in[8];
    const float* ln_g   = (const float*)d_in[9];
    const float* ln_bt  = (const float*)d_in[10];
    const float* W_out  = (const float*)d_in[11];
    float* out = (float*)d_out;

    char* p = (char*)d_ws;
    bf16* z_bf     = (bf16*)p;  p += (size_t)NTOK*DINNER*2;   // 50.3 MB
    bf16* xbc_pre  = (bf16*)p;  p += (size_t)NTOK*CONVD*2;    // 54.5 MB
    bf16* xbc_post = (bf16*)p;  p += (size_t)NTOK*CONVD*2;    // 54.5 MB
    float* cq_pre  = (float*)p; p += (size_t)NTOK*DST*4;      //  4.2 MB
    float* cq_post = (float*)p; p += (size_t)NTOK*DST*4;      //  4.2 MB
    float* dA      = (float*)p; p += (size_t)NTOK*NH*4;       //  8.4 MB
    bf16* yz       = (bf16*)p;  p += (size_t)NTOK*DINNER*2;   // 50.3 MB
    float* kv      = (float*)p; p += (size_t)BN*NH*DST*HD*4;  // 98 KB
    bf16* Win_bf   = (bf16*)p;  p += (size_t)832*DMODEL*2;    // 320 KB
    bf16* Wout_bf  = (bf16*)p;  p += (size_t)DMODEL*DINNER*2; // 148 KB

    hipMemsetAsync(kv, 0, (size_t)BN*NH*DST*HD*4, stream);
    k_prep<<<624, 256, 0, stream>>>(Win, W_out, Win_bf, Wout_bf);
    k_proj_mfma<<<512, 256, 0, stream>>>(u, Win_bf, dt_b, A_log, z_bf, xbc_pre, dA);
    k_tproj<<<NTOK/16, 256, 0, stream>>>(t, Wtin, cq_pre);
    k_conv416<<<NTOK/2, 448, 0, stream>>>(xbc_pre, conv_w, conv_b, xbc_post);
    k_conv16<<<NTOK*16/256, 256, 0, stream>>>(cq_pre, conv_w, conv_b, cq_post);
    k_kv<<<dim3(64, BN), 512, 0, stream>>>(xbc_post, dA, kv);
    k_ynorm<<<NTOK/16, 256, 0, stream>>>(xbc_post, cq_post, z_bf, kv,
                                         Dv, ln_g, ln_bt, yz);
    k_out_mfma<<<512, 256, 0, stream>>>(yz, Wout_bf, out);
}

// Round 3
// 429.657 us; speedup vs baseline: 2.2326x; 1.2267x over previous
//
#include <hip/hip_runtime.h>
#include <hip/hip_bf16.h>
#include <math.h>

// Mamba2 fused block, round 3: k_kv restructured (16-token barrier batches,
// no atomics, two-stage partial reduction). GEMMs unchanged from round 2.

#define BN 4
#define HH 128
#define WWID 128
#define LTOK (HH*WWID)          // 16384
#define NTOK (BN*LTOK)          // 65536
#define DMODEL 192
#define DINNER 384
#define NH 32
#define HD 12
#define DST 16
#define CONVD 416               // D_INNER + 2*16
#define KVCHUNKS 64             // L-chunks per batch for k_kv

typedef __hip_bfloat16 bf16;
typedef unsigned int uint32;
typedef unsigned short ushort16;
typedef __attribute__((ext_vector_type(8))) short bf16x8;
typedef __attribute__((ext_vector_type(4))) float f32x4;

__device__ __forceinline__ float bflo(uint32 v){ return __uint_as_float((v & 0xffffu) << 16); }
__device__ __forceinline__ float bfhi(uint32 v){ return __uint_as_float(v & 0xffff0000u); }
__device__ __forceinline__ ushort16 f2bf(float f){
    __hip_bfloat16 h = __float2bfloat16(f);
    return *reinterpret_cast<const ushort16*>(&h);
}
__device__ __forceinline__ float softplusf(float x){
    return (x > 20.f) ? x : log1pf(expf(x));
}
__device__ __forceinline__ float siluf(float x){
    return x / (1.f + expf(-x));
}

union BFPK { short s[8]; bf16x8 v; };

// ---------------------------------------------------------------------------
// k_prep: convert Win (832x192) and Wout (192x384) to bf16.
// ---------------------------------------------------------------------------
__global__ __launch_bounds__(256) void k_prep(
    const float* __restrict__ Win, const float* __restrict__ Wout,
    bf16* __restrict__ Winbf, bf16* __restrict__ Woutbf)
{
    const int i = blockIdx.x*256 + threadIdx.x;
    if (i < 832*DMODEL)   Winbf[i]  = __float2bfloat16(Win[i]);
    if (i < DMODEL*DINNER) Woutbf[i] = __float2bfloat16(Wout[i]);
}

// ---------------------------------------------------------------------------
// k_proj_mfma: zxbcdt = u @ Win^T via 16x16x32 bf16 MFMA. (unchanged r2)
// ---------------------------------------------------------------------------
__global__ __launch_bounds__(256) void k_proj_mfma(
    const float* __restrict__ u, const bf16* __restrict__ Wbf,
    const float* __restrict__ dt_b, const float* __restrict__ A_log,
    bf16* __restrict__ z_bf, bf16* __restrict__ xbc_pre, float* __restrict__ dA)
{
    __shared__ __align__(16) short As[128*200];
    __shared__ __align__(16) short Bs[2][128*40];

    const int tid = threadIdx.x;
    const int m0 = blockIdx.x * 128;
    const int wid = tid >> 6, lane = tid & 63;
    const int wm = wid >> 1, wn = wid & 1;
    const int fr = lane & 15, fq = lane >> 4;

    // ---- stage A: 128x192 f32 -> bf16 LDS, 2 threads/row ----
    {
        const int row = tid >> 1, half = tid & 1;
        const float* src = u + (size_t)(m0 + row)*DMODEL + half*96;
        short* dst = &As[row*200 + half*96];
        #pragma unroll
        for (int i = 0; i < 12; ++i) {
            const float4 a0 = *(const float4*)(src + i*8);
            const float4 a1 = *(const float4*)(src + i*8 + 4);
            BFPK pk;
            pk.s[0]=(short)f2bf(a0.x); pk.s[1]=(short)f2bf(a0.y);
            pk.s[2]=(short)f2bf(a0.z); pk.s[3]=(short)f2bf(a0.w);
            pk.s[4]=(short)f2bf(a1.x); pk.s[5]=(short)f2bf(a1.y);
            pk.s[6]=(short)f2bf(a1.z); pk.s[7]=(short)f2bf(a1.w);
            *(bf16x8*)(dst + i*8) = pk.v;
        }
    }

    const int brow = tid >> 1, bhalf = tid & 1;
    auto stageB = [&](int nt, int ks, int buf) {
        const int ch = nt*128 + brow;
        uint4 v0 = make_uint4(0,0,0,0), v1 = make_uint4(0,0,0,0);
        if (ch < 832) {
            const short* g = (const short*)Wbf + (size_t)ch*DMODEL + ks*32 + bhalf*16;
            v0 = *(const uint4*)g;
            v1 = *(const uint4*)(g + 8);
        }
        short* d = &Bs[buf][brow*40 + bhalf*16];
        *(uint4*)d = v0;
        *(uint4*)(d + 8) = v1;
    };

    stageB(0, 0, 0);
    __syncthreads();

    const short* Ab = &As[(wm*64 + fr)*200 + fq*8];
    const int boff = (wn*64 + fr)*40 + fq*8;

    for (int nt = 0; nt < 7; ++nt) {
        f32x4 acc[4][4];
        #pragma unroll
        for (int mi=0;mi<4;++mi)
            #pragma unroll
            for (int ni=0;ni<4;++ni) acc[mi][ni] = (f32x4){0.f,0.f,0.f,0.f};

        #pragma unroll
        for (int ks = 0; ks < 6; ++ks) {
            const int cur = ks & 1;
            if (ks < 5)          stageB(nt,   ks+1, cur^1);
            else if (nt < 6)     stageB(nt+1, 0,    cur^1);

            bf16x8 a[4], b[4];
            #pragma unroll
            for (int mi=0;mi<4;++mi) a[mi] = *(const bf16x8*)(Ab + mi*3200 + ks*32);
            #pragma unroll
            for (int ni=0;ni<4;++ni) b[ni] = *(const bf16x8*)(&Bs[cur][boff + ni*640]);
            #pragma unroll
            for (int mi=0;mi<4;++mi)
                #pragma unroll
                for (int ni=0;ni<4;++ni)
                    acc[mi][ni] = __builtin_amdgcn_mfma_f32_16x16x32_bf16(a[mi], b[ni], acc[mi][ni], 0, 0, 0);
            __syncthreads();
        }

        #pragma unroll
        for (int ni=0;ni<4;++ni) {
            const int n = nt*128 + wn*64 + ni*16 + fr;
            #pragma unroll
            for (int mi=0;mi<4;++mi) {
                #pragma unroll
                for (int j=0;j<4;++j) {
                    const int tok = m0 + wm*64 + mi*16 + fq*4 + j;
                    const float v = acc[mi][ni][j];
                    if (n < DINNER) {
                        z_bf[(size_t)tok*DINNER + n] = __float2bfloat16(v);
                    } else if (n < DINNER + CONVD) {
                        xbc_pre[(size_t)tok*CONVD + (n - DINNER)] = __float2bfloat16(v);
                    } else if (n < 832) {
                        const int hh = n - (DINNER + CONVD);
                        const float dt = softplusf(v + dt_b[hh]);
                        dA[(size_t)tok*NH + hh] = dt * expf(A_log[hh]);
                    }
                }
            }
        }
    }
}

// ---------------------------------------------------------------------------
// k_tproj: cq_pre[tok][n] = t[tok] . Wtin[784+n], n=0..15. 16 tokens/block.
// ---------------------------------------------------------------------------
__global__ __launch_bounds__(256) void k_tproj(
    const float* __restrict__ t, const float* __restrict__ Wtin, float* __restrict__ cq_pre)
{
    __shared__ float ts[16][196];
    __shared__ float ws[16][196];
    const int tid = threadIdx.x;
    const int tok0 = blockIdx.x * 16;
    #pragma unroll
    for (int i = 0; i < 3; ++i) {
        const int flat = tid + 256*i;          // 0..767
        const int row = flat / 48, c = (flat % 48)*4;
        *(float4*)&ts[row][c] = *(const float4*)(t    + (size_t)(tok0+row)*DMODEL + c);
        *(float4*)&ws[row][c] = *(const float4*)(Wtin + (size_t)(784+row)*DMODEL + c);
    }
    __syncthreads();
    const int tt = tid >> 4, n = tid & 15;
    float s0=0.f,s1=0.f,s2=0.f,s3=0.f;
    #pragma unroll 4
    for (int k = 0; k < DMODEL; k += 4) {
        s0 = fmaf(ts[tt][k+0], ws[n][k+0], s0);
        s1 = fmaf(ts[tt][k+1], ws[n][k+1], s1);
        s2 = fmaf(ts[tt][k+2], ws[n][k+2], s2);
        s3 = fmaf(ts[tt][k+3], ws[n][k+3], s3);
    }
    cq_pre[(size_t)(tok0+tt)*DST + n] = (s0+s1)+(s2+s3);
}

// ---------------------------------------------------------------------------
// k_conv416: depthwise 3x3 SAME conv + bias + SiLU over 416 channels.
// ---------------------------------------------------------------------------
__global__ __launch_bounds__(448) void k_conv416(
    const bf16* __restrict__ in, const float* __restrict__ cw, const float* __restrict__ cb,
    bf16* __restrict__ out)
{
    const int tid = threadIdx.x;
    if (tid >= 416) return;
    const int pl = (tid >= 208) ? 1 : 0;
    const int c2 = tid - pl*208;
    const int c  = c2*2;
    const int pix = blockIdx.x*2 + pl;
    const int hw = pix & (LTOK-1);
    const int h = hw >> 7;
    const int w = hw & 127;
    const int bb = pix >> 14;

    float w0[9], w1[9];
    #pragma unroll
    for (int k=0;k<9;++k){ w0[k]=cw[c*9+k]; w1[k]=cw[(c+1)*9+k]; }
    float a0 = cb[c], a1 = cb[c+1];

    #pragma unroll
    for (int dh=-1; dh<=1; ++dh) {
        const int hh = h + dh;
        if ((unsigned)hh >= (unsigned)HH) continue;
        #pragma unroll
        for (int dw=-1; dw<=1; ++dw) {
            const int w2 = w + dw;
            if ((unsigned)w2 >= (unsigned)WWID) continue;
            const size_t off = ((size_t)((bb<<14) + (hh<<7) + w2))*CONVD + c;
            const uint32 v = *(const uint32*)((const ushort16*)in + off);
            const int wi = (dh+1)*3 + (dw+1);
            a0 = fmaf(bflo(v), w0[wi], a0);
            a1 = fmaf(bfhi(v), w1[wi], a1);
        }
    }
    const uint32 o = ((uint32)f2bf(siluf(a1)) << 16) | (uint32)f2bf(siluf(a0));
    *(uint32*)((ushort16*)out + (size_t)pix*CONVD + c) = o;
}

// ---------------------------------------------------------------------------
// k_conv16: same conv for the 16 Cq channels (conv channels 400..415), f32.
// ---------------------------------------------------------------------------
__global__ __launch_bounds__(256) void k_conv16(
    const float* __restrict__ in, const float* __restrict__ cw, const float* __restrict__ cb,
    float* __restrict__ out)
{
    const int idx = blockIdx.x*256 + threadIdx.x;   // NTOK*16
    const int cc = idx & 15;
    const int pix = idx >> 4;
    const int hw = pix & (LTOK-1);
    const int h = hw >> 7, w = hw & 127;
    const int bb = pix >> 14;
    const int c = 400 + cc;

    float wg[9];
    #pragma unroll
    for (int k=0;k<9;++k) wg[k] = cw[c*9+k];
    float a = cb[c];
    #pragma unroll
    for (int dh=-1; dh<=1; ++dh) {
        const int hh = h + dh;
        if ((unsigned)hh >= (unsigned)HH) continue;
        #pragma unroll
        for (int dw=-1; dw<=1; ++dw) {
            const int w2 = w + dw;
            if ((unsigned)w2 >= (unsigned)WWID) continue;
            a = fmaf(in[((size_t)((bb<<14)+(hh<<7)+w2))*16 + cc], wg[(dh+1)*3 + (dw+1)], a);
        }
    }
    out[(size_t)pix*16 + cc] = siluf(a);
}

// ---------------------------------------------------------------------------
// k_kv: partial KV per (batch, 256-token chunk). 16 tokens staged per barrier
// (raw bf16 copy), dA scaling folded into compute. No atomics: each block
// writes a 6144-float partial; k_kvred sums the 64 chunks.
// thread (n = tid&15, g = tid>>4) accumulates 12 d-values.
// ---------------------------------------------------------------------------
__global__ __launch_bounds__(512) void k_kv(
    const bf16* __restrict__ xbc_post, const float* __restrict__ dA,
    float* __restrict__ partial)
{
    __shared__ short vsb[16][408];   // 16 tokens x 400 ch (bf16 raw), +8 pad
    __shared__ float das[16][32];
    const int tid = threadIdx.x;
    const int b = blockIdx.y;
    const int n = tid & 15;
    const int g = tid >> 4;          // head

    float acc[12];
    #pragma unroll
    for (int j=0;j<12;++j) acc[j]=0.f;

    const int l0base = b*LTOK + blockIdx.x*256;

    for (int it = 0; it < 16; ++it) {
        const int l0 = l0base + it*16;
        // stage 16 tokens x 400 channels (dword copies, coalesced)
        for (int i = tid; i < 16*200; i += 512) {
            const int tok = i / 200;
            const int c2 = i - tok*200;
            const uint32 v = *(const uint32*)((const ushort16*)xbc_post
                                + (size_t)(l0+tok)*CONVD + c2*2);
            *(uint32*)&vsb[tok][c2*2] = v;
        }
        {
            const int tok = tid >> 5, h = tid & 31;
            das[tok][h] = dA[(size_t)(l0+tok)*NH + h];
        }
        __syncthreads();

        #pragma unroll
        for (int tok = 0; tok < 16; ++tok) {
            const uint32 bkraw = (uint32)(ushort16)vsb[tok][DINNER + n];
            const float s = __uint_as_float(bkraw << 16) * das[tok][g];
            const uint32* vp = (const uint32*)&vsb[tok][g*12];
            const uint32 w0 = vp[0], w1 = vp[1], w2 = vp[2];
            acc[0]  = fmaf(s, bflo(w0), acc[0]);
            acc[1]  = fmaf(s, bfhi(w0), acc[1]);
            acc[2]  = fmaf(s, bflo(w1), acc[2]);
            acc[3]  = fmaf(s, bfhi(w1), acc[3]);
            acc[4]  = fmaf(s, bflo(w2), acc[4]);
            acc[5]  = fmaf(s, bfhi(w2), acc[5]);
            const uint32* vq = (const uint32*)&vsb[tok][g*12 + 6];
            const uint32 w3 = vq[0], w4 = vq[1], w5 = vq[2];
            acc[6]  = fmaf(s, bflo(w3), acc[6]);
            acc[7]  = fmaf(s, bfhi(w3), acc[7]);
            acc[8]  = fmaf(s, bflo(w4), acc[8]);
            acc[9]  = fmaf(s, bfhi(w4), acc[9]);
            acc[10] = fmaf(s, bflo(w5), acc[10]);
            acc[11] = fmaf(s, bfhi(w5), acc[11]);
        }
        __syncthreads();
    }

    // partial layout: [b*64+chunk][g*192 + n*12 + d]  (matches kv flat order)
    float* dst = partial + ((size_t)(b*KVCHUNKS + blockIdx.x))*6144 + (size_t)tid*12;
    #pragma unroll
    for (int j4=0;j4<3;++j4)
        *(float4*)(dst + j4*4) = make_float4(acc[j4*4], acc[j4*4+1], acc[j4*4+2], acc[j4*4+3]);
}

// ---------------------------------------------------------------------------
// k_kvred: kv[b][flat] = sum_{c<64} partial[b*64+c][flat].  24576 threads.
// ---------------------------------------------------------------------------
__global__ __launch_bounds__(256) void k_kvred(
    const float* __restrict__ partial, float* __restrict__ kv)
{
    const int idx = blockIdx.x*256 + threadIdx.x;   // 4*6144
    const int b = idx / 6144;
    const int flat = idx - b*6144;
    const float* p = partial + (size_t)(b*KVCHUNKS)*6144 + flat;
    float s = 0.f;
    #pragma unroll 4
    for (int c = 0; c < KVCHUNKS; ++c) s += p[(size_t)c*6144];
    kv[idx] = s;
}

// ---------------------------------------------------------------------------
// k_ynorm: y = Cq @ KV + V*D, LayerNorm(384), gate by z -> yz (bf16).
// ---------------------------------------------------------------------------
__global__ __launch_bounds__(256) void k_ynorm(
    const bf16* __restrict__ xbc_post, const float* __restrict__ cq_post,
    const bf16* __restrict__ z_bf, const float* __restrict__ kv,
    const float* __restrict__ Dv, const float* __restrict__ ln_g, const float* __restrict__ ln_b,
    bf16* __restrict__ yz)
{
    __shared__ float kvs[NH*DST*HD];   // 6144, layout [n][hd]
    __shared__ float ys[16][386];
    __shared__ float cqs[16][16];
    const int tid = threadIdx.x;
    const int token0 = blockIdx.x * 16;
    const int b = token0 >> 14;

    for (int i = tid; i < NH*DST*HD; i += 256) {
        const int n = i / DINNER;
        const int hd = i - n*DINNER;
        const int h = hd / HD;
        const int d = hd - h*HD;
        kvs[i] = kv[((size_t)(b*NH + h)*DST + n)*HD + d];
    }
    {
        const int tt = tid >> 4, n2 = tid & 15;
        cqs[tt][n2] = cq_post[(size_t)(token0+tt)*DST + n2];
    }
    __syncthreads();

    #pragma unroll
    for (int jj=0; jj<12; ++jj) {
        const int flat = jj*256 + tid;     // 0..3071 (pairs)
        const int tt = flat / 192;
        const int p  = flat - tt*192;
        const int hd = p*2;
        const int h = hd / HD;
        const int l = token0 + tt;
        const uint32 v = *(const uint32*)((const ushort16*)xbc_post + (size_t)l*CONVD + hd);
        const float dv = Dv[h];
        float a0 = bflo(v) * dv;
        float a1 = bfhi(v) * dv;
        #pragma unroll
        for (int n=0;n<16;++n) {
            const float c = cqs[tt][n];
            const float2 kk = *(const float2*)&kvs[n*DINNER + hd];
            a0 = fmaf(c, kk.x, a0);
            a1 = fmaf(c, kk.y, a1);
        }
        *(float2*)&ys[tt][hd] = make_float2(a0, a1);
    }
    __syncthreads();

    const int wave = tid >> 6, lane = tid & 63;
    #pragma unroll
    for (int i=0;i<4;++i) {
        const int tt = wave*4 + i;
        const int l = token0 + tt;
        float v[6]; float s=0.f, s2=0.f;
        #pragma unroll
        for (int k=0;k<6;++k){ const float x = ys[tt][k*64+lane]; v[k]=x; s+=x; s2=fmaf(x,x,s2); }
        #pragma unroll
        for (int off=32; off>0; off>>=1){ s += __shfl_xor(s,off,64); s2 += __shfl_xor(s2,off,64); }
        const float mu = s*(1.f/384.f);
        const float var = s2*(1.f/384.f) - mu*mu;
        const float rs = rsqrtf(var + 1e-5f);
        #pragma unroll
        for (int k=0;k<6;++k){
            const int idx = k*64+lane;
            const float yn = (v[k]-mu)*rs*ln_g[idx] + ln_b[idx];
            const uint32 zb = (uint32)(*((const ushort16*)z_bf + (size_t)l*DINNER + idx));
            const float zv = __uint_as_float(zb << 16);
            yz[(size_t)l*DINNER + idx] = __float2bfloat16(yn*zv);
        }
    }
}

// ---------------------------------------------------------------------------
// k_out_mfma: out = yz @ Wout^T via MFMA. (unchanged r2)
// ---------------------------------------------------------------------------
__global__ __launch_bounds__(256) void k_out_mfma(
    const bf16* __restrict__ yz, const bf16* __restrict__ Wbf, float* __restrict__ out)
{
    __shared__ __align__(16) short As[2][128*40];
    __shared__ __align__(16) short Bs[2][192*40];

    const int tid = threadIdx.x;
    const int m0 = blockIdx.x * 128;
    const int wid = tid >> 6, lane = tid & 63;
    const int wm = wid >> 1, wn = wid & 1;
    const int fr = lane & 15, fq = lane >> 4;

    const int arow = tid >> 1, ahalf = tid & 1;
    auto stageA = [&](int ks, int buf) {
        const short* g = (const short*)yz + (size_t)(m0 + arow)*DINNER + ks*32 + ahalf*16;
        const uint4 v0 = *(const uint4*)g;
        const uint4 v1 = *(const uint4*)(g + 8);
        short* d = &As[buf][arow*40 + ahalf*16];
        *(uint4*)d = v0;
        *(uint4*)(d + 8) = v1;
    };
    auto stageB = [&](int ks, int buf) {
        #pragma unroll
        for (int i = 0; i < 3; ++i) {
            const int flat = tid + 256*i;      // 0..767
            const int row = flat >> 2, q = flat & 3;
            const uint4 v = *(const uint4*)((const short*)Wbf + (size_t)row*DINNER + ks*32 + q*8);
            *(uint4*)&Bs[buf][row*40 + q*8] = v;
        }
    };

    f32x4 acc[4][6];
    #pragma unroll
    for (int mi=0;mi<4;++mi)
        #pragma unroll
        for (int ni=0;ni<6;++ni) acc[mi][ni] = (f32x4){0.f,0.f,0.f,0.f};

    stageA(0, 0); stageB(0, 0);
    __syncthreads();

    const int aoff = (wm*64 + fr)*40 + fq*8;
    const int boff = (wn*96 + fr)*40 + fq*8;

    #pragma unroll
    for (int ks = 0; ks < 12; ++ks) {
        const int cur = ks & 1;
        if (ks < 11) { stageA(ks+1, cur^1); stageB(ks+1, cur^1); }
        bf16x8 a[4], b[6];
        #pragma unroll
        for (int mi=0;mi<4;++mi) a[mi] = *(const bf16x8*)(&As[cur][aoff + mi*640]);
        #pragma unroll
        for (int ni=0;ni<6;++ni) b[ni] = *(const bf16x8*)(&Bs[cur][boff + ni*640]);
        #pragma unroll
        for (int mi=0;mi<4;++mi)
            #pragma unroll
            for (int ni=0;ni<6;++ni)
                acc[mi][ni] = __builtin_amdgcn_mfma_f32_16x16x32_bf16(a[mi], b[ni], acc[mi][ni], 0, 0, 0);
        __syncthreads();
    }

    #pragma unroll
    for (int mi=0;mi<4;++mi) {
        #pragma unroll
        for (int j=0;j<4;++j) {
            const int tok = m0 + wm*64 + mi*16 + fq*4 + j;
            #pragma unroll
            for (int ni=0;ni<6;++ni) {
                const int n = wn*96 + ni*16 + fr;
                out[(size_t)tok*DMODEL + n] = acc[mi][ni][j];
            }
        }
    }
}

// ---------------------------------------------------------------------------
extern "C" void kernel_launch(void* const* d_in, const int* in_sizes, int n_in,
                              void* d_out, int out_size, void* d_ws, size_t ws_size,
                              hipStream_t stream)
{
    const float* u      = (const float*)d_in[0];
    const float* t      = (const float*)d_in[1];
    const float* Win    = (const float*)d_in[2];
    const float* Wtin   = (const float*)d_in[3];
    const float* conv_w = (const float*)d_in[4];
    const float* conv_b = (const float*)d_in[5];
    const float* dt_b   = (const float*)d_in[6];
    const float* A_log  = (const float*)d_in[7];
    const float* Dv     = (const float*)d_in[8];
    const float* ln_g   = (const float*)d_in[9];
    const float* ln_bt  = (const float*)d_in[10];
    const float* W_out  = (const float*)d_in[11];
    float* out = (float*)d_out;

    char* p = (char*)d_ws;
    bf16* z_bf     = (bf16*)p;  p += (size_t)NTOK*DINNER*2;   // 50.3 MB
    bf16* xbc_pre  = (bf16*)p;  p += (size_t)NTOK*CONVD*2;    // 54.5 MB (reused as kv partials after conv)
    bf16* xbc_post = (bf16*)p;  p += (size_t)NTOK*CONVD*2;    // 54.5 MB
    float* cq_pre  = (float*)p; p += (size_t)NTOK*DST*4;      //  4.2 MB
    float* cq_post = (float*)p; p += (size_t)NTOK*DST*4;      //  4.2 MB
    float* dA      = (float*)p; p += (size_t)NTOK*NH*4;       //  8.4 MB
    bf16* yz       = (bf16*)p;  p += (size_t)NTOK*DINNER*2;   // 50.3 MB
    float* kv      = (float*)p; p += (size_t)BN*NH*DST*HD*4;  // 98 KB
    bf16* Win_bf   = (bf16*)p;  p += (size_t)832*DMODEL*2;    // 320 KB
    bf16* Wout_bf  = (bf16*)p;  p += (size_t)DMODEL*DINNER*2; // 148 KB

    float* kv_part = (float*)xbc_pre;   // 6.3 MB, xbc_pre dead after k_conv416

    k_prep<<<624, 256, 0, stream>>>(Win, W_out, Win_bf, Wout_bf);
    k_proj_mfma<<<512, 256, 0, stream>>>(u, Win_bf, dt_b, A_log, z_bf, xbc_pre, dA);
    k_tproj<<<NTOK/16, 256, 0, stream>>>(t, Wtin, cq_pre);
    k_conv416<<<NTOK/2, 448, 0, stream>>>(xbc_pre, conv_w, conv_b, xbc_post);
    k_conv16<<<NTOK*16/256, 256, 0, stream>>>(cq_pre, conv_w, conv_b, cq_post);
    k_kv<<<dim3(KVCHUNKS, BN), 512, 0, stream>>>(xbc_post, dA, kv_part);
    k_kvred<<<BN*6144/256, 256, 0, stream>>>(kv_part, kv);
    k_ynorm<<<NTOK/16, 256, 0, stream>>>(xbc_post, cq_post, z_bf, kv,
                                         Dv, ln_g, ln_bt, yz);
    k_out_mfma<<<512, 256, 0, stream>>>(yz, Wout_bf, out);
}

// Round 6
// 371.478 us; speedup vs baseline: 2.5822x; 1.1566x over previous
//
#include <hip/hip_runtime.h>
#include <hip/hip_bf16.h>
#include <math.h>

// Mamba2 fused block, round 6: round-5 structure with the stage-B copy bug
// fixed (uint4 stores advance 8 shorts, not 16 — half of B was stale A data).
// k_proj: full-K LDS tile, A-frags in registers, S reused A->B, stride 200.

#define BN 4
#define HH 128
#define WWID 128
#define LTOK (HH*WWID)          // 16384
#define NTOK (BN*LTOK)          // 65536
#define DMODEL 192
#define DINNER 384
#define NH 32
#define HD 12
#define DST 16
#define CONVD 416               // D_INNER + 2*16
#define KVCHUNKS 64             // L-chunks per batch for k_kv
#define PSTR 200                // k_proj LDS row stride in shorts (16B-aligned)

typedef __hip_bfloat16 bf16;
typedef unsigned int uint32;
typedef unsigned short ushort16;
typedef __attribute__((ext_vector_type(8))) short bf16x8;
typedef __attribute__((ext_vector_type(4))) float f32x4;

__device__ __forceinline__ float bflo(uint32 v){ return __uint_as_float((v & 0xffffu) << 16); }
__device__ __forceinline__ float bfhi(uint32 v){ return __uint_as_float(v & 0xffff0000u); }
__device__ __forceinline__ ushort16 f2bf(float f){
    __hip_bfloat16 h = __float2bfloat16(f);
    return *reinterpret_cast<const ushort16*>(&h);
}
__device__ __forceinline__ float softplusf(float x){
    return (x > 20.f) ? x : log1pf(expf(x));
}
__device__ __forceinline__ float siluf(float x){
    return x / (1.f + expf(-x));
}

union BFPK { short s[8]; bf16x8 v; };

// ---------------------------------------------------------------------------
// k_prep: convert Win (832x192) and Wout (192x384) to bf16.
// ---------------------------------------------------------------------------
__global__ __launch_bounds__(256) void k_prep(
    const float* __restrict__ Win, const float* __restrict__ Wout,
    bf16* __restrict__ Winbf, bf16* __restrict__ Woutbf)
{
    const int i = blockIdx.x*256 + threadIdx.x;
    if (i < 832*DMODEL)   Winbf[i]  = __float2bfloat16(Win[i]);
    if (i < DMODEL*DINNER) Woutbf[i] = __float2bfloat16(Wout[i]);
}

// ---------------------------------------------------------------------------
// k_proj_mfma: zxbcdt = u @ Win^T via 16x16x32 bf16 MFMA.
// Block = 128 tokens x 832 out-channels. Single LDS buffer S[128][PSTR]
// (51.2 KB -> 3 blocks/CU). Stage A once, lift A-frags to registers, then
// per N-tile: stage B (full K), 96 MFMAs/wave, wave-uniform epilogue.
// ---------------------------------------------------------------------------
__global__ __launch_bounds__(256) void k_proj_mfma(
    const float* __restrict__ u, const bf16* __restrict__ Wbf,
    const float* __restrict__ dt_b, const float* __restrict__ A_log,
    bf16* __restrict__ z_bf, bf16* __restrict__ xbc_pre, float* __restrict__ dA)
{
    __shared__ __align__(16) short S[128*PSTR];   // 51.2 KB, reused A -> B

    const int tid = threadIdx.x;
    const int m0 = blockIdx.x * 128;
    const int wid = tid >> 6, lane = tid & 63;
    const int fr = lane & 15, fq = lane >> 4;

    // ---- stage A: 128x192 f32 -> bf16, 2 threads/row ----
    {
        const int row = tid >> 1, half = tid & 1;
        const float* src = u + (size_t)(m0 + row)*DMODEL + half*96;
        short* dst = &S[row*PSTR + half*96];
        #pragma unroll
        for (int i = 0; i < 12; ++i) {
            const float4 a0 = *(const float4*)(src + i*8);
            const float4 a1 = *(const float4*)(src + i*8 + 4);
            BFPK pk;
            pk.s[0]=(short)f2bf(a0.x); pk.s[1]=(short)f2bf(a0.y);
            pk.s[2]=(short)f2bf(a0.z); pk.s[3]=(short)f2bf(a0.w);
            pk.s[4]=(short)f2bf(a1.x); pk.s[5]=(short)f2bf(a1.y);
            pk.s[6]=(short)f2bf(a1.z); pk.s[7]=(short)f2bf(a1.w);
            *(bf16x8*)(dst + i*8) = pk.v;
        }
    }
    __syncthreads();

    // ---- lift A-fragments: wave wid owns tokens [wid*32, wid*32+32) ----
    bf16x8 a[2][6];
    #pragma unroll
    for (int mi=0;mi<2;++mi)
        #pragma unroll
        for (int ks=0;ks<6;++ks)
            a[mi][ks] = *(const bf16x8*)&S[(wid*32 + mi*16 + fr)*PSTR + ks*32 + fq*8];
    __syncthreads();   // S (A) dead

    for (int nt = 0; nt < 7; ++nt) {
        // ---- stage B(nt): 128 channels x 192 k, raw bf16 copy ----
        // NOTE: pointers are short*; each uint4 covers 8 shorts, so paired
        // stores advance by 16 shorts per iteration (contiguous 96 shorts).
        {
            const int row = tid >> 1, half = tid & 1;
            const int ch = nt*128 + row;
            if (ch < 832) {
                const short* g = (const short*)Wbf + (size_t)ch*DMODEL + half*96;
                short* d = &S[row*PSTR + half*96];
                #pragma unroll
                for (int i=0;i<6;++i) {
                    *(uint4*)(d + i*16)     = *(const uint4*)(g + i*16);
                    *(uint4*)(d + i*16 + 8) = *(const uint4*)(g + i*16 + 8);
                }
            }
        }
        __syncthreads();

        f32x4 acc[2][8];
        #pragma unroll
        for (int mi=0;mi<2;++mi)
            #pragma unroll
            for (int ni=0;ni<8;++ni) acc[mi][ni] = (f32x4){0.f,0.f,0.f,0.f};

        #pragma unroll
        for (int ks=0;ks<6;++ks) {
            bf16x8 b[8];
            #pragma unroll
            for (int ni=0;ni<8;++ni)
                b[ni] = *(const bf16x8*)&S[(ni*16 + fr)*PSTR + ks*32 + fq*8];
            #pragma unroll
            for (int mi=0;mi<2;++mi)
                #pragma unroll
                for (int ni=0;ni<8;++ni)
                    acc[mi][ni] = __builtin_amdgcn_mfma_f32_16x16x32_bf16(a[mi][ks], b[ni], acc[mi][ni], 0, 0, 0);
        }
        __syncthreads();   // before next nt overwrites S

        // ---- epilogue: region uniform per (nt, ni) since boundaries are x16 ----
        #pragma unroll
        for (int ni=0;ni<8;++ni) {
            const int idx16 = nt*8 + ni;          // 16-col group index
            if (idx16 >= 52) continue;            // beyond 832
            const int n = idx16*16 + fr;
            #pragma unroll
            for (int mi=0;mi<2;++mi) {
                #pragma unroll
                for (int j=0;j<4;++j) {
                    const int tok = m0 + wid*32 + mi*16 + fq*4 + j;
                    const float v = acc[mi][ni][j];
                    if (idx16 < 24) {
                        z_bf[(size_t)tok*DINNER + n] = __float2bfloat16(v);
                    } else if (idx16 < 50) {
                        xbc_pre[(size_t)tok*CONVD + (n - DINNER)] = __float2bfloat16(v);
                    } else {
                        const int hh = n - 800;
                        const float dt = softplusf(v + dt_b[hh]);
                        dA[(size_t)tok*NH + hh] = dt * expf(A_log[hh]);
                    }
                }
            }
        }
    }
}

// ---------------------------------------------------------------------------
// k_tproj: cq_pre[tok][n] = t[tok] . Wtin[784+n], n=0..15. 16 tokens/block.
// ---------------------------------------------------------------------------
__global__ __launch_bounds__(256) void k_tproj(
    const float* __restrict__ t, const float* __restrict__ Wtin, float* __restrict__ cq_pre)
{
    __shared__ float ts[16][196];
    __shared__ float ws[16][196];
    const int tid = threadIdx.x;
    const int tok0 = blockIdx.x * 16;
    #pragma unroll
    for (int i = 0; i < 3; ++i) {
        const int flat = tid + 256*i;          // 0..767
        const int row = flat / 48, c = (flat % 48)*4;
        *(float4*)&ts[row][c] = *(const float4*)(t    + (size_t)(tok0+row)*DMODEL + c);
        *(float4*)&ws[row][c] = *(const float4*)(Wtin + (size_t)(784+row)*DMODEL + c);
    }
    __syncthreads();
    const int tt = tid >> 4, n = tid & 15;
    float s0=0.f,s1=0.f,s2=0.f,s3=0.f;
    #pragma unroll 4
    for (int k = 0; k < DMODEL; k += 4) {
        s0 = fmaf(ts[tt][k+0], ws[n][k+0], s0);
        s1 = fmaf(ts[tt][k+1], ws[n][k+1], s1);
        s2 = fmaf(ts[tt][k+2], ws[n][k+2], s2);
        s3 = fmaf(ts[tt][k+3], ws[n][k+3], s3);
    }
    cq_pre[(size_t)(tok0+tt)*DST + n] = (s0+s1)+(s2+s3);
}

// ---------------------------------------------------------------------------
// k_conv416: depthwise 3x3 SAME conv + bias + SiLU over 416 channels.
// ---------------------------------------------------------------------------
__global__ __launch_bounds__(448) void k_conv416(
    const bf16* __restrict__ in, const float* __restrict__ cw, const float* __restrict__ cb,
    bf16* __restrict__ out)
{
    const int tid = threadIdx.x;
    if (tid >= 416) return;
    const int pl = (tid >= 208) ? 1 : 0;
    const int c2 = tid - pl*208;
    const int c  = c2*2;
    const int pix = blockIdx.x*2 + pl;
    const int hw = pix & (LTOK-1);
    const int h = hw >> 7;
    const int w = hw & 127;
    const int bb = pix >> 14;

    float w0[9], w1[9];
    #pragma unroll
    for (int k=0;k<9;++k){ w0[k]=cw[c*9+k]; w1[k]=cw[(c+1)*9+k]; }
    float a0 = cb[c], a1 = cb[c+1];

    #pragma unroll
    for (int dh=-1; dh<=1; ++dh) {
        const int hh = h + dh;
        if ((unsigned)hh >= (unsigned)HH) continue;
        #pragma unroll
        for (int dw=-1; dw<=1; ++dw) {
            const int w2 = w + dw;
            if ((unsigned)w2 >= (unsigned)WWID) continue;
            const size_t off = ((size_t)((bb<<14) + (hh<<7) + w2))*CONVD + c;
            const uint32 v = *(const uint32*)((const ushort16*)in + off);
            const int wi = (dh+1)*3 + (dw+1);
            a0 = fmaf(bflo(v), w0[wi], a0);
            a1 = fmaf(bfhi(v), w1[wi], a1);
        }
    }
    const uint32 o = ((uint32)f2bf(siluf(a1)) << 16) | (uint32)f2bf(siluf(a0));
    *(uint32*)((ushort16*)out + (size_t)pix*CONVD + c) = o;
}

// ---------------------------------------------------------------------------
// k_conv16: same conv for the 16 Cq channels (conv channels 400..415), f32.
// ---------------------------------------------------------------------------
__global__ __launch_bounds__(256) void k_conv16(
    const float* __restrict__ in, const float* __restrict__ cw, const float* __restrict__ cb,
    float* __restrict__ out)
{
    const int idx = blockIdx.x*256 + threadIdx.x;   // NTOK*16
    const int cc = idx & 15;
    const int pix = idx >> 4;
    const int hw = pix & (LTOK-1);
    const int h = hw >> 7, w = hw & 127;
    const int bb = pix >> 14;
    const int c = 400 + cc;

    float wg[9];
    #pragma unroll
    for (int k=0;k<9;++k) wg[k] = cw[c*9+k];
    float a = cb[c];
    #pragma unroll
    for (int dh=-1; dh<=1; ++dh) {
        const int hh = h + dh;
        if ((unsigned)hh >= (unsigned)HH) continue;
        #pragma unroll
        for (int dw=-1; dw<=1; ++dw) {
            const int w2 = w + dw;
            if ((unsigned)w2 >= (unsigned)WWID) continue;
            a = fmaf(in[((size_t)((bb<<14)+(hh<<7)+w2))*16 + cc], wg[(dh+1)*3 + (dw+1)], a);
        }
    }
    out[(size_t)pix*16 + cc] = siluf(a);
}

// ---------------------------------------------------------------------------
// k_kv: partial KV per (batch, 256-token chunk). 16 tokens staged per barrier
// (raw bf16 copy), dA scaling folded into compute. No atomics.
// ---------------------------------------------------------------------------
__global__ __launch_bounds__(512) void k_kv(
    const bf16* __restrict__ xbc_post, const float* __restrict__ dA,
    float* __restrict__ partial)
{
    __shared__ short vsb[16][408];   // 16 tokens x 400 ch (bf16 raw), +8 pad
    __shared__ float das[16][32];
    const int tid = threadIdx.x;
    const int b = blockIdx.y;
    const int n = tid & 15;
    const int g = tid >> 4;          // head

    float acc[12];
    #pragma unroll
    for (int j=0;j<12;++j) acc[j]=0.f;

    const int l0base = b*LTOK + blockIdx.x*256;

    for (int it = 0; it < 16; ++it) {
        const int l0 = l0base + it*16;
        for (int i = tid; i < 16*200; i += 512) {
            const int tok = i / 200;
            const int c2 = i - tok*200;
            const uint32 v = *(const uint32*)((const ushort16*)xbc_post
                                + (size_t)(l0+tok)*CONVD + c2*2);
            *(uint32*)&vsb[tok][c2*2] = v;
        }
        {
            const int tok = tid >> 5, h = tid & 31;
            das[tok][h] = dA[(size_t)(l0+tok)*NH + h];
        }
        __syncthreads();

        #pragma unroll
        for (int tok = 0; tok < 16; ++tok) {
            const uint32 bkraw = (uint32)(ushort16)vsb[tok][DINNER + n];
            const float s = __uint_as_float(bkraw << 16) * das[tok][g];
            const uint32* vp = (const uint32*)&vsb[tok][g*12];
            const uint32 w0 = vp[0], w1 = vp[1], w2 = vp[2];
            acc[0]  = fmaf(s, bflo(w0), acc[0]);
            acc[1]  = fmaf(s, bfhi(w0), acc[1]);
            acc[2]  = fmaf(s, bflo(w1), acc[2]);
            acc[3]  = fmaf(s, bfhi(w1), acc[3]);
            acc[4]  = fmaf(s, bflo(w2), acc[4]);
            acc[5]  = fmaf(s, bfhi(w2), acc[5]);
            const uint32* vq = (const uint32*)&vsb[tok][g*12 + 6];
            const uint32 w3 = vq[0], w4 = vq[1], w5 = vq[2];
            acc[6]  = fmaf(s, bflo(w3), acc[6]);
            acc[7]  = fmaf(s, bfhi(w3), acc[7]);
            acc[8]  = fmaf(s, bflo(w4), acc[8]);
            acc[9]  = fmaf(s, bfhi(w4), acc[9]);
            acc[10] = fmaf(s, bflo(w5), acc[10]);
            acc[11] = fmaf(s, bfhi(w5), acc[11]);
        }
        __syncthreads();
    }

    float* dst = partial + ((size_t)(b*KVCHUNKS + blockIdx.x))*6144 + (size_t)tid*12;
    #pragma unroll
    for (int j4=0;j4<3;++j4)
        *(float4*)(dst + j4*4) = make_float4(acc[j4*4], acc[j4*4+1], acc[j4*4+2], acc[j4*4+3]);
}

// ---------------------------------------------------------------------------
// k_kvred: kv[b][flat] = sum_{c<64} partial[b*64+c][flat].
// ---------------------------------------------------------------------------
__global__ __launch_bounds__(256) void k_kvred(
    const float* __restrict__ partial, float* __restrict__ kv)
{
    const int idx = blockIdx.x*256 + threadIdx.x;   // 4*6144
    const int b = idx / 6144;
    const int flat = idx - b*6144;
    const float* p = partial + (size_t)(b*KVCHUNKS)*6144 + flat;
    float s = 0.f;
    #pragma unroll 4
    for (int c = 0; c < KVCHUNKS; ++c) s += p[(size_t)c*6144];
    kv[idx] = s;
}

// ---------------------------------------------------------------------------
// k_ynorm: y = Cq @ KV + V*D, LayerNorm(384), gate by z -> yz (bf16).
// ---------------------------------------------------------------------------
__global__ __launch_bounds__(256) void k_ynorm(
    const bf16* __restrict__ xbc_post, const float* __restrict__ cq_post,
    const bf16* __restrict__ z_bf, const float* __restrict__ kv,
    const float* __restrict__ Dv, const float* __restrict__ ln_g, const float* __restrict__ ln_b,
    bf16* __restrict__ yz)
{
    __shared__ float kvs[NH*DST*HD];   // 6144, layout [n][hd]
    __shared__ float ys[16][386];
    __shared__ float cqs[16][16];
    const int tid = threadIdx.x;
    const int token0 = blockIdx.x * 16;
    const int b = token0 >> 14;

    for (int i = tid; i < NH*DST*HD; i += 256) {
        const int n = i / DINNER;
        const int hd = i - n*DINNER;
        const int h = hd / HD;
        const int d = hd - h*HD;
        kvs[i] = kv[((size_t)(b*NH + h)*DST + n)*HD + d];
    }
    {
        const int tt = tid >> 4, n2 = tid & 15;
        cqs[tt][n2] = cq_post[(size_t)(token0+tt)*DST + n2];
    }
    __syncthreads();

    #pragma unroll
    for (int jj=0; jj<12; ++jj) {
        const int flat = jj*256 + tid;     // 0..3071 (pairs)
        const int tt = flat / 192;
        const int p  = flat - tt*192;
        const int hd = p*2;
        const int h = hd / HD;
        const int l = token0 + tt;
        const uint32 v = *(const uint32*)((const ushort16*)xbc_post + (size_t)l*CONVD + hd);
        const float dv = Dv[h];
        float a0 = bflo(v) * dv;
        float a1 = bfhi(v) * dv;
        #pragma unroll
        for (int n=0;n<16;++n) {
            const float c = cqs[tt][n];
            const float2 kk = *(const float2*)&kvs[n*DINNER + hd];
            a0 = fmaf(c, kk.x, a0);
            a1 = fmaf(c, kk.y, a1);
        }
        *(float2*)&ys[tt][hd] = make_float2(a0, a1);
    }
    __syncthreads();

    const int wave = tid >> 6, lane = tid & 63;
    #pragma unroll
    for (int i=0;i<4;++i) {
        const int tt = wave*4 + i;
        const int l = token0 + tt;
        float v[6]; float s=0.f, s2=0.f;
        #pragma unroll
        for (int k=0;k<6;++k){ const float x = ys[tt][k*64+lane]; v[k]=x; s+=x; s2=fmaf(x,x,s2); }
        #pragma unroll
        for (int off=32; off>0; off>>=1){ s += __shfl_xor(s,off,64); s2 += __shfl_xor(s2,off,64); }
        const float mu = s*(1.f/384.f);
        const float var = s2*(1.f/384.f) - mu*mu;
        const float rs = rsqrtf(var + 1e-5f);
        #pragma unroll
        for (int k=0;k<6;++k){
            const int idx = k*64+lane;
            const float yn = (v[k]-mu)*rs*ln_g[idx] + ln_b[idx];
            const uint32 zb = (uint32)(*((const ushort16*)z_bf + (size_t)l*DINNER + idx));
            const float zv = __uint_as_float(zb << 16);
            yz[(size_t)l*DINNER + idx] = __float2bfloat16(yn*zv);
        }
    }
}

// ---------------------------------------------------------------------------
// k_out_mfma: out = yz @ Wout^T via MFMA. (unchanged r2)
// ---------------------------------------------------------------------------
__global__ __launch_bounds__(256) void k_out_mfma(
    const bf16* __restrict__ yz, const bf16* __restrict__ Wbf, float* __restrict__ out)
{
    __shared__ __align__(16) short As[2][128*40];
    __shared__ __align__(16) short Bs[2][192*40];

    const int tid = threadIdx.x;
    const int m0 = blockIdx.x * 128;
    const int wid = tid >> 6, lane = tid & 63;
    const int wm = wid >> 1, wn = wid & 1;
    const int fr = lane & 15, fq = lane >> 4;

    const int arow = tid >> 1, ahalf = tid & 1;
    auto stageA = [&](int ks, int buf) {
        const short* g = (const short*)yz + (size_t)(m0 + arow)*DINNER + ks*32 + ahalf*16;
        const uint4 v0 = *(const uint4*)g;
        const uint4 v1 = *(const uint4*)(g + 8);
        short* d = &As[buf][arow*40 + ahalf*16];
        *(uint4*)d = v0;
        *(uint4*)(d + 8) = v1;
    };
    auto stageB = [&](int ks, int buf) {
        #pragma unroll
        for (int i = 0; i < 3; ++i) {
            const int flat = tid + 256*i;      // 0..767
            const int row = flat >> 2, q = flat & 3;
            const uint4 v = *(const uint4*)((const short*)Wbf + (size_t)row*DINNER + ks*32 + q*8);
            *(uint4*)&Bs[buf][row*40 + q*8] = v;
        }
    };

    f32x4 acc[4][6];
    #pragma unroll
    for (int mi=0;mi<4;++mi)
        #pragma unroll
        for (int ni=0;ni<6;++ni) acc[mi][ni] = (f32x4){0.f,0.f,0.f,0.f};

    stageA(0, 0); stageB(0, 0);
    __syncthreads();

    const int aoff = (wm*64 + fr)*40 + fq*8;
    const int boff = (wn*96 + fr)*40 + fq*8;

    #pragma unroll
    for (int ks = 0; ks < 12; ++ks) {
        const int cur = ks & 1;
        if (ks < 11) { stageA(ks+1, cur^1); stageB(ks+1, cur^1); }
        bf16x8 a[4], b[6];
        #pragma unroll
        for (int mi=0;mi<4;++mi) a[mi] = *(const bf16x8*)(&As[cur][aoff + mi*640]);
        #pragma unroll
        for (int ni=0;ni<6;++ni) b[ni] = *(const bf16x8*)(&Bs[cur][boff + ni*640]);
        #pragma unroll
        for (int mi=0;mi<4;++mi)
            #pragma unroll
            for (int ni=0;ni<6;++ni)
                acc[mi][ni] = __builtin_amdgcn_mfma_f32_16x16x32_bf16(a[mi], b[ni], acc[mi][ni], 0, 0, 0);
        __syncthreads();
    }

    #pragma unroll
    for (int mi=0;mi<4;++mi) {
        #pragma unroll
        for (int j=0;j<4;++j) {
            const int tok = m0 + wm*64 + mi*16 + fq*4 + j;
            #pragma unroll
            for (int ni=0;ni<6;++ni) {
                const int n = wn*96 + ni*16 + fr;
                out[(size_t)tok*DMODEL + n] = acc[mi][ni][j];
            }
        }
    }
}

// ---------------------------------------------------------------------------
extern "C" void kernel_launch(void* const* d_in, const int* in_sizes, int n_in,
                              void* d_out, int out_size, void* d_ws, size_t ws_size,
                              hipStream_t stream)
{
    const float* u      = (const float*)d_in[0];
    const float* t      = (const float*)d_in[1];
    const float* Win    = (const float*)d_in[2];
    const float* Wtin   = (const float*)d_in[3];
    const float* conv_w = (const float*)d_in[4];
    const float* conv_b = (const float*)d_in[5];
    const float* dt_b   = (const float*)d_in[6];
    const float* A_log  = (const float*)d_in[7];
    const float* Dv     = (const float*)d_in[8];
    const float* ln_g   = (const float*)d_in[9];
    const float* ln_bt  = (const float*)d_in[10];
    const float* W_out  = (const float*)d_in[11];
    float* out = (float*)d_out;

    char* p = (char*)d_ws;
    bf16* z_bf     = (bf16*)p;  p += (size_t)NTOK*DINNER*2;   // 50.3 MB
    bf16* xbc_pre  = (bf16*)p;  p += (size_t)NTOK*CONVD*2;    // 54.5 MB (reused as kv partials after conv)
    bf16* xbc_post = (bf16*)p;  p += (size_t)NTOK*CONVD*2;    // 54.5 MB
    float* cq_pre  = (float*)p; p += (size_t)NTOK*DST*4;      //  4.2 MB
    float* cq_post = (float*)p; p += (size_t)NTOK*DST*4;      //  4.2 MB
    float* dA      = (float*)p; p += (size_t)NTOK*NH*4;       //  8.4 MB
    bf16* yz       = (bf16*)p;  p += (size_t)NTOK*DINNER*2;   // 50.3 MB
    float* kv      = (float*)p; p += (size_t)BN*NH*DST*HD*4;  // 98 KB
    bf16* Win_bf   = (bf16*)p;  p += (size_t)832*DMODEL*2;    // 320 KB
    bf16* Wout_bf  = (bf16*)p;  p += (size_t)DMODEL*DINNER*2; // 148 KB

    float* kv_part = (float*)xbc_pre;   // 6.3 MB, xbc_pre dead after k_conv416

    k_prep<<<624, 256, 0, stream>>>(Win, W_out, Win_bf, Wout_bf);
    k_proj_mfma<<<512, 256, 0, stream>>>(u, Win_bf, dt_b, A_log, z_bf, xbc_pre, dA);
    k_tproj<<<NTOK/16, 256, 0, stream>>>(t, Wtin, cq_pre);
    k_conv416<<<NTOK/2, 448, 0, stream>>>(xbc_pre, conv_w, conv_b, xbc_post);
    k_conv16<<<NTOK*16/256, 256, 0, stream>>>(cq_pre, conv_w, conv_b, cq_post);
    k_kv<<<dim3(KVCHUNKS, BN), 512, 0, stream>>>(xbc_post, dA, kv_part);
    k_kvred<<<BN*6144/256, 256, 0, stream>>>(kv_part, kv);
    k_ynorm<<<NTOK/16, 256, 0, stream>>>(xbc_post, cq_post, z_bf, kv,
                                         Dv, ln_g, ln_bt, yz);
    k_out_mfma<<<512, 256, 0, stream>>>(yz, Wout_bf, out);
}

// Round 7
// 318.116 us; speedup vs baseline: 3.0154x; 1.1677x over previous
//
#include <hip/hip_runtime.h>
#include <hip/hip_bf16.h>
#include <math.h>

// Mamba2 fused block, round 7: k_conv416 vectorized 8-ch/thread (uint4 loads,
// LDS-staged transposed weights). Other kernels unchanged from round 6.

#define BN 4
#define HH 128
#define WWID 128
#define LTOK (HH*WWID)          // 16384
#define NTOK (BN*LTOK)          // 65536
#define DMODEL 192
#define DINNER 384
#define NH 32
#define HD 12
#define DST 16
#define CONVD 416               // D_INNER + 2*16
#define KVCHUNKS 64             // L-chunks per batch for k_kv
#define PSTR 200                // k_proj LDS row stride in shorts (16B-aligned)

typedef __hip_bfloat16 bf16;
typedef unsigned int uint32;
typedef unsigned short ushort16;
typedef __attribute__((ext_vector_type(8))) short bf16x8;
typedef __attribute__((ext_vector_type(4))) float f32x4;

__device__ __forceinline__ float bflo(uint32 v){ return __uint_as_float((v & 0xffffu) << 16); }
__device__ __forceinline__ float bfhi(uint32 v){ return __uint_as_float(v & 0xffff0000u); }
__device__ __forceinline__ ushort16 f2bf(float f){
    __hip_bfloat16 h = __float2bfloat16(f);
    return *reinterpret_cast<const ushort16*>(&h);
}
__device__ __forceinline__ float softplusf(float x){
    return (x > 20.f) ? x : log1pf(expf(x));
}
__device__ __forceinline__ float siluf(float x){
    return x / (1.f + expf(-x));
}

union BFPK { short s[8]; bf16x8 v; };

// ---------------------------------------------------------------------------
// k_prep: convert Win (832x192), Wout (192x384) to bf16; transpose conv
// weights to wtr[9][420] f32 (tap-major, padded).
// ---------------------------------------------------------------------------
__global__ __launch_bounds__(256) void k_prep(
    const float* __restrict__ Win, const float* __restrict__ Wout,
    const float* __restrict__ cw,
    bf16* __restrict__ Winbf, bf16* __restrict__ Woutbf, float* __restrict__ wtr)
{
    const int i = blockIdx.x*256 + threadIdx.x;
    if (i < 832*DMODEL)   Winbf[i]  = __float2bfloat16(Win[i]);
    if (i < DMODEL*DINNER) Woutbf[i] = __float2bfloat16(Wout[i]);
    if (i < CONVD*9) { const int c = i/9, k = i - c*9; wtr[k*420 + c] = cw[i]; }
}

// ---------------------------------------------------------------------------
// k_proj_mfma: zxbcdt = u @ Win^T via 16x16x32 bf16 MFMA. (unchanged r6)
// ---------------------------------------------------------------------------
__global__ __launch_bounds__(256) void k_proj_mfma(
    const float* __restrict__ u, const bf16* __restrict__ Wbf,
    const float* __restrict__ dt_b, const float* __restrict__ A_log,
    bf16* __restrict__ z_bf, bf16* __restrict__ xbc_pre, float* __restrict__ dA)
{
    __shared__ __align__(16) short S[128*PSTR];   // 51.2 KB, reused A -> B

    const int tid = threadIdx.x;
    const int m0 = blockIdx.x * 128;
    const int wid = tid >> 6, lane = tid & 63;
    const int fr = lane & 15, fq = lane >> 4;

    // ---- stage A: 128x192 f32 -> bf16, 2 threads/row ----
    {
        const int row = tid >> 1, half = tid & 1;
        const float* src = u + (size_t)(m0 + row)*DMODEL + half*96;
        short* dst = &S[row*PSTR + half*96];
        #pragma unroll
        for (int i = 0; i < 12; ++i) {
            const float4 a0 = *(const float4*)(src + i*8);
            const float4 a1 = *(const float4*)(src + i*8 + 4);
            BFPK pk;
            pk.s[0]=(short)f2bf(a0.x); pk.s[1]=(short)f2bf(a0.y);
            pk.s[2]=(short)f2bf(a0.z); pk.s[3]=(short)f2bf(a0.w);
            pk.s[4]=(short)f2bf(a1.x); pk.s[5]=(short)f2bf(a1.y);
            pk.s[6]=(short)f2bf(a1.z); pk.s[7]=(short)f2bf(a1.w);
            *(bf16x8*)(dst + i*8) = pk.v;
        }
    }
    __syncthreads();

    // ---- lift A-fragments: wave wid owns tokens [wid*32, wid*32+32) ----
    bf16x8 a[2][6];
    #pragma unroll
    for (int mi=0;mi<2;++mi)
        #pragma unroll
        for (int ks=0;ks<6;++ks)
            a[mi][ks] = *(const bf16x8*)&S[(wid*32 + mi*16 + fr)*PSTR + ks*32 + fq*8];
    __syncthreads();   // S (A) dead

    for (int nt = 0; nt < 7; ++nt) {
        // ---- stage B(nt): 128 channels x 192 k, raw bf16 copy ----
        {
            const int row = tid >> 1, half = tid & 1;
            const int ch = nt*128 + row;
            if (ch < 832) {
                const short* g = (const short*)Wbf + (size_t)ch*DMODEL + half*96;
                short* d = &S[row*PSTR + half*96];
                #pragma unroll
                for (int i=0;i<6;++i) {
                    *(uint4*)(d + i*16)     = *(const uint4*)(g + i*16);
                    *(uint4*)(d + i*16 + 8) = *(const uint4*)(g + i*16 + 8);
                }
            }
        }
        __syncthreads();

        f32x4 acc[2][8];
        #pragma unroll
        for (int mi=0;mi<2;++mi)
            #pragma unroll
            for (int ni=0;ni<8;++ni) acc[mi][ni] = (f32x4){0.f,0.f,0.f,0.f};

        #pragma unroll
        for (int ks=0;ks<6;++ks) {
            bf16x8 b[8];
            #pragma unroll
            for (int ni=0;ni<8;++ni)
                b[ni] = *(const bf16x8*)&S[(ni*16 + fr)*PSTR + ks*32 + fq*8];
            #pragma unroll
            for (int mi=0;mi<2;++mi)
                #pragma unroll
                for (int ni=0;ni<8;++ni)
                    acc[mi][ni] = __builtin_amdgcn_mfma_f32_16x16x32_bf16(a[mi][ks], b[ni], acc[mi][ni], 0, 0, 0);
        }
        __syncthreads();   // before next nt overwrites S

        // ---- epilogue: region uniform per (nt, ni) since boundaries are x16 ----
        #pragma unroll
        for (int ni=0;ni<8;++ni) {
            const int idx16 = nt*8 + ni;          // 16-col group index
            if (idx16 >= 52) continue;            // beyond 832
            const int n = idx16*16 + fr;
            #pragma unroll
            for (int mi=0;mi<2;++mi) {
                #pragma unroll
                for (int j=0;j<4;++j) {
                    const int tok = m0 + wid*32 + mi*16 + fq*4 + j;
                    const float v = acc[mi][ni][j];
                    if (idx16 < 24) {
                        z_bf[(size_t)tok*DINNER + n] = __float2bfloat16(v);
                    } else if (idx16 < 50) {
                        xbc_pre[(size_t)tok*CONVD + (n - DINNER)] = __float2bfloat16(v);
                    } else {
                        const int hh = n - 800;
                        const float dt = softplusf(v + dt_b[hh]);
                        dA[(size_t)tok*NH + hh] = dt * expf(A_log[hh]);
                    }
                }
            }
        }
    }
}

// ---------------------------------------------------------------------------
// k_tproj: cq_pre[tok][n] = t[tok] . Wtin[784+n], n=0..15. 16 tokens/block.
// ---------------------------------------------------------------------------
__global__ __launch_bounds__(256) void k_tproj(
    const float* __restrict__ t, const float* __restrict__ Wtin, float* __restrict__ cq_pre)
{
    __shared__ float ts[16][196];
    __shared__ float ws[16][196];
    const int tid = threadIdx.x;
    const int tok0 = blockIdx.x * 16;
    #pragma unroll
    for (int i = 0; i < 3; ++i) {
        const int flat = tid + 256*i;          // 0..767
        const int row = flat / 48, c = (flat % 48)*4;
        *(float4*)&ts[row][c] = *(const float4*)(t    + (size_t)(tok0+row)*DMODEL + c);
        *(float4*)&ws[row][c] = *(const float4*)(Wtin + (size_t)(784+row)*DMODEL + c);
    }
    __syncthreads();
    const int tt = tid >> 4, n = tid & 15;
    float s0=0.f,s1=0.f,s2=0.f,s3=0.f;
    #pragma unroll 4
    for (int k = 0; k < DMODEL; k += 4) {
        s0 = fmaf(ts[tt][k+0], ws[n][k+0], s0);
        s1 = fmaf(ts[tt][k+1], ws[n][k+1], s1);
        s2 = fmaf(ts[tt][k+2], ws[n][k+2], s2);
        s3 = fmaf(ts[tt][k+3], ws[n][k+3], s3);
    }
    cq_pre[(size_t)(tok0+tt)*DST + n] = (s0+s1)+(s2+s3);
}

// ---------------------------------------------------------------------------
// k_conv416: depthwise 3x3 SAME conv + bias + SiLU, 8 channels/thread.
// Block = 416 threads: 8 pixels (same image row) x 52 channel-groups.
// Weights staged to LDS from transposed wtr[9][420]; input loads are b128.
// ---------------------------------------------------------------------------
__global__ __launch_bounds__(416) void k_conv416(
    const bf16* __restrict__ in, const float* __restrict__ wtr, const float* __restrict__ cb,
    bf16* __restrict__ out)
{
    __shared__ float ws[9*420];    // 15.1 KB
    __shared__ float bs[416];
    const int tid = threadIdx.x;
    for (int i = tid; i < 9*420; i += 416) ws[i] = wtr[i];
    if (tid < 416) bs[tid] = cb[tid];
    __syncthreads();

    const int pl  = tid / 52;
    const int grp = tid - pl*52;
    const int c0  = grp*8;
    const int pix = blockIdx.x*8 + pl;
    const int hw  = pix & (LTOK-1);
    const int h = hw >> 7, w = hw & 127;
    const int bb = pix >> 14;

    float acc[8];
    {
        const float4 b0 = *(const float4*)&bs[c0];
        const float4 b1 = *(const float4*)&bs[c0+4];
        acc[0]=b0.x; acc[1]=b0.y; acc[2]=b0.z; acc[3]=b0.w;
        acc[4]=b1.x; acc[5]=b1.y; acc[6]=b1.z; acc[7]=b1.w;
    }

    #pragma unroll
    for (int dh=-1; dh<=1; ++dh) {
        const int hh = h + dh;
        if ((unsigned)hh >= (unsigned)HH) continue;
        #pragma unroll
        for (int dw=-1; dw<=1; ++dw) {
            const int w2 = w + dw;
            if ((unsigned)w2 >= (unsigned)WWID) continue;
            const int wi = (dh+1)*3 + (dw+1);
            const size_t off = ((size_t)((bb<<14) + (hh<<7) + w2))*CONVD + c0;
            const uint4 v = *(const uint4*)((const ushort16*)in + off);
            const float4 w0 = *(const float4*)&ws[wi*420 + c0];
            const float4 w1 = *(const float4*)&ws[wi*420 + c0 + 4];
            acc[0] = fmaf(bflo(v.x), w0.x, acc[0]);
            acc[1] = fmaf(bfhi(v.x), w0.y, acc[1]);
            acc[2] = fmaf(bflo(v.y), w0.z, acc[2]);
            acc[3] = fmaf(bfhi(v.y), w0.w, acc[3]);
            acc[4] = fmaf(bflo(v.z), w1.x, acc[4]);
            acc[5] = fmaf(bfhi(v.z), w1.y, acc[5]);
            acc[6] = fmaf(bflo(v.w), w1.z, acc[6]);
            acc[7] = fmaf(bfhi(v.w), w1.w, acc[7]);
        }
    }

    uint4 o;
    o.x = ((uint32)f2bf(siluf(acc[1])) << 16) | (uint32)f2bf(siluf(acc[0]));
    o.y = ((uint32)f2bf(siluf(acc[3])) << 16) | (uint32)f2bf(siluf(acc[2]));
    o.z = ((uint32)f2bf(siluf(acc[5])) << 16) | (uint32)f2bf(siluf(acc[4]));
    o.w = ((uint32)f2bf(siluf(acc[7])) << 16) | (uint32)f2bf(siluf(acc[6]));
    *(uint4*)((ushort16*)out + (size_t)pix*CONVD + c0) = o;
}

// ---------------------------------------------------------------------------
// k_conv16: same conv for the 16 Cq channels (conv channels 400..415), f32.
// ---------------------------------------------------------------------------
__global__ __launch_bounds__(256) void k_conv16(
    const float* __restrict__ in, const float* __restrict__ cw, const float* __restrict__ cb,
    float* __restrict__ out)
{
    const int idx = blockIdx.x*256 + threadIdx.x;   // NTOK*16
    const int cc = idx & 15;
    const int pix = idx >> 4;
    const int hw = pix & (LTOK-1);
    const int h = hw >> 7, w = hw & 127;
    const int bb = pix >> 14;
    const int c = 400 + cc;

    float wg[9];
    #pragma unroll
    for (int k=0;k<9;++k) wg[k] = cw[c*9+k];
    float a = cb[c];
    #pragma unroll
    for (int dh=-1; dh<=1; ++dh) {
        const int hh = h + dh;
        if ((unsigned)hh >= (unsigned)HH) continue;
        #pragma unroll
        for (int dw=-1; dw<=1; ++dw) {
            const int w2 = w + dw;
            if ((unsigned)w2 >= (unsigned)WWID) continue;
            a = fmaf(in[((size_t)((bb<<14)+(hh<<7)+w2))*16 + cc], wg[(dh+1)*3 + (dw+1)], a);
        }
    }
    out[(size_t)pix*16 + cc] = siluf(a);
}

// ---------------------------------------------------------------------------
// k_kv: partial KV per (batch, 256-token chunk). 16 tokens staged per barrier
// (raw bf16 copy), dA scaling folded into compute. No atomics.
// ---------------------------------------------------------------------------
__global__ __launch_bounds__(512) void k_kv(
    const bf16* __restrict__ xbc_post, const float* __restrict__ dA,
    float* __restrict__ partial)
{
    __shared__ short vsb[16][408];   // 16 tokens x 400 ch (bf16 raw), +8 pad
    __shared__ float das[16][32];
    const int tid = threadIdx.x;
    const int b = blockIdx.y;
    const int n = tid & 15;
    const int g = tid >> 4;          // head

    float acc[12];
    #pragma unroll
    for (int j=0;j<12;++j) acc[j]=0.f;

    const int l0base = b*LTOK + blockIdx.x*256;

    for (int it = 0; it < 16; ++it) {
        const int l0 = l0base + it*16;
        for (int i = tid; i < 16*200; i += 512) {
            const int tok = i / 200;
            const int c2 = i - tok*200;
            const uint32 v = *(const uint32*)((const ushort16*)xbc_post
                                + (size_t)(l0+tok)*CONVD + c2*2);
            *(uint32*)&vsb[tok][c2*2] = v;
        }
        {
            const int tok = tid >> 5, h = tid & 31;
            das[tok][h] = dA[(size_t)(l0+tok)*NH + h];
        }
        __syncthreads();

        #pragma unroll
        for (int tok = 0; tok < 16; ++tok) {
            const uint32 bkraw = (uint32)(ushort16)vsb[tok][DINNER + n];
            const float s = __uint_as_float(bkraw << 16) * das[tok][g];
            const uint32* vp = (const uint32*)&vsb[tok][g*12];
            const uint32 w0 = vp[0], w1 = vp[1], w2 = vp[2];
            acc[0]  = fmaf(s, bflo(w0), acc[0]);
            acc[1]  = fmaf(s, bfhi(w0), acc[1]);
            acc[2]  = fmaf(s, bflo(w1), acc[2]);
            acc[3]  = fmaf(s, bfhi(w1), acc[3]);
            acc[4]  = fmaf(s, bflo(w2), acc[4]);
            acc[5]  = fmaf(s, bfhi(w2), acc[5]);
            const uint32* vq = (const uint32*)&vsb[tok][g*12 + 6];
            const uint32 w3 = vq[0], w4 = vq[1], w5 = vq[2];
            acc[6]  = fmaf(s, bflo(w3), acc[6]);
            acc[7]  = fmaf(s, bfhi(w3), acc[7]);
            acc[8]  = fmaf(s, bflo(w4), acc[8]);
            acc[9]  = fmaf(s, bfhi(w4), acc[9]);
            acc[10] = fmaf(s, bflo(w5), acc[10]);
            acc[11] = fmaf(s, bfhi(w5), acc[11]);
        }
        __syncthreads();
    }

    float* dst = partial + ((size_t)(b*KVCHUNKS + blockIdx.x))*6144 + (size_t)tid*12;
    #pragma unroll
    for (int j4=0;j4<3;++j4)
        *(float4*)(dst + j4*4) = make_float4(acc[j4*4], acc[j4*4+1], acc[j4*4+2], acc[j4*4+3]);
}

// ---------------------------------------------------------------------------
// k_kvred: kv[b][flat] = sum_{c<64} partial[b*64+c][flat].
// ---------------------------------------------------------------------------
__global__ __launch_bounds__(256) void k_kvred(
    const float* __restrict__ partial, float* __restrict__ kv)
{
    const int idx = blockIdx.x*256 + threadIdx.x;   // 4*6144
    const int b = idx / 6144;
    const int flat = idx - b*6144;
    const float* p = partial + (size_t)(b*KVCHUNKS)*6144 + flat;
    float s = 0.f;
    #pragma unroll 4
    for (int c = 0; c < KVCHUNKS; ++c) s += p[(size_t)c*6144];
    kv[idx] = s;
}

// ---------------------------------------------------------------------------
// k_ynorm: y = Cq @ KV + V*D, LayerNorm(384), gate by z -> yz (bf16).
// ---------------------------------------------------------------------------
__global__ __launch_bounds__(256) void k_ynorm(
    const bf16* __restrict__ xbc_post, const float* __restrict__ cq_post,
    const bf16* __restrict__ z_bf, const float* __restrict__ kv,
    const float* __restrict__ Dv, const float* __restrict__ ln_g, const float* __restrict__ ln_b,
    bf16* __restrict__ yz)
{
    __shared__ float kvs[NH*DST*HD];   // 6144, layout [n][hd]
    __shared__ float ys[16][386];
    __shared__ float cqs[16][16];
    const int tid = threadIdx.x;
    const int token0 = blockIdx.x * 16;
    const int b = token0 >> 14;

    for (int i = tid; i < NH*DST*HD; i += 256) {
        const int n = i / DINNER;
        const int hd = i - n*DINNER;
        const int h = hd / HD;
        const int d = hd - h*HD;
        kvs[i] = kv[((size_t)(b*NH + h)*DST + n)*HD + d];
    }
    {
        const int tt = tid >> 4, n2 = tid & 15;
        cqs[tt][n2] = cq_post[(size_t)(token0+tt)*DST + n2];
    }
    __syncthreads();

    #pragma unroll
    for (int jj=0; jj<12; ++jj) {
        const int flat = jj*256 + tid;     // 0..3071 (pairs)
        const int tt = flat / 192;
        const int p  = flat - tt*192;
        const int hd = p*2;
        const int h = hd / HD;
        const int l = token0 + tt;
        const uint32 v = *(const uint32*)((const ushort16*)xbc_post + (size_t)l*CONVD + hd);
        const float dv = Dv[h];
        float a0 = bflo(v) * dv;
        float a1 = bfhi(v) * dv;
        #pragma unroll
        for (int n=0;n<16;++n) {
            const float c = cqs[tt][n];
            const float2 kk = *(const float2*)&kvs[n*DINNER + hd];
            a0 = fmaf(c, kk.x, a0);
            a1 = fmaf(c, kk.y, a1);
        }
        *(float2*)&ys[tt][hd] = make_float2(a0, a1);
    }
    __syncthreads();

    const int wave = tid >> 6, lane = tid & 63;
    #pragma unroll
    for (int i=0;i<4;++i) {
        const int tt = wave*4 + i;
        const int l = token0 + tt;
        float v[6]; float s=0.f, s2=0.f;
        #pragma unroll
        for (int k=0;k<6;++k){ const float x = ys[tt][k*64+lane]; v[k]=x; s+=x; s2=fmaf(x,x,s2); }
        #pragma unroll
        for (int off=32; off>0; off>>=1){ s += __shfl_xor(s,off,64); s2 += __shfl_xor(s2,off,64); }
        const float mu = s*(1.f/384.f);
        const float var = s2*(1.f/384.f) - mu*mu;
        const float rs = rsqrtf(var + 1e-5f);
        #pragma unroll
        for (int k=0;k<6;++k){
            const int idx = k*64+lane;
            const float yn = (v[k]-mu)*rs*ln_g[idx] + ln_b[idx];
            const uint32 zb = (uint32)(*((const ushort16*)z_bf + (size_t)l*DINNER + idx));
            const float zv = __uint_as_float(zb << 16);
            yz[(size_t)l*DINNER + idx] = __float2bfloat16(yn*zv);
        }
    }
}

// ---------------------------------------------------------------------------
// k_out_mfma: out = yz @ Wout^T via MFMA. (unchanged r2)
// ---------------------------------------------------------------------------
__global__ __launch_bounds__(256) void k_out_mfma(
    const bf16* __restrict__ yz, const bf16* __restrict__ Wbf, float* __restrict__ out)
{
    __shared__ __align__(16) short As[2][128*40];
    __shared__ __align__(16) short Bs[2][192*40];

    const int tid = threadIdx.x;
    const int m0 = blockIdx.x * 128;
    const int wid = tid >> 6, lane = tid & 63;
    const int wm = wid >> 1, wn = wid & 1;
    const int fr = lane & 15, fq = lane >> 4;

    const int arow = tid >> 1, ahalf = tid & 1;
    auto stageA = [&](int ks, int buf) {
        const short* g = (const short*)yz + (size_t)(m0 + arow)*DINNER + ks*32 + ahalf*16;
        const uint4 v0 = *(const uint4*)g;
        const uint4 v1 = *(const uint4*)(g + 8);
        short* d = &As[buf][arow*40 + ahalf*16];
        *(uint4*)d = v0;
        *(uint4*)(d + 8) = v1;
    };
    auto stageB = [&](int ks, int buf) {
        #pragma unroll
        for (int i = 0; i < 3; ++i) {
            const int flat = tid + 256*i;      // 0..767
            const int row = flat >> 2, q = flat & 3;
            const uint4 v = *(const uint4*)((const short*)Wbf + (size_t)row*DINNER + ks*32 + q*8);
            *(uint4*)&Bs[buf][row*40 + q*8] = v;
        }
    };

    f32x4 acc[4][6];
    #pragma unroll
    for (int mi=0;mi<4;++mi)
        #pragma unroll
        for (int ni=0;ni<6;++ni) acc[mi][ni] = (f32x4){0.f,0.f,0.f,0.f};

    stageA(0, 0); stageB(0, 0);
    __syncthreads();

    const int aoff = (wm*64 + fr)*40 + fq*8;
    const int boff = (wn*96 + fr)*40 + fq*8;

    #pragma unroll
    for (int ks = 0; ks < 12; ++ks) {
        const int cur = ks & 1;
        if (ks < 11) { stageA(ks+1, cur^1); stageB(ks+1, cur^1); }
        bf16x8 a[4], b[6];
        #pragma unroll
        for (int mi=0;mi<4;++mi) a[mi] = *(const bf16x8*)(&As[cur][aoff + mi*640]);
        #pragma unroll
        for (int ni=0;ni<6;++ni) b[ni] = *(const bf16x8*)(&Bs[cur][boff + ni*640]);
        #pragma unroll
        for (int mi=0;mi<4;++mi)
            #pragma unroll
            for (int ni=0;ni<6;++ni)
                acc[mi][ni] = __builtin_amdgcn_mfma_f32_16x16x32_bf16(a[mi], b[ni], acc[mi][ni], 0, 0, 0);
        __syncthreads();
    }

    #pragma unroll
    for (int mi=0;mi<4;++mi) {
        #pragma unroll
        for (int j=0;j<4;++j) {
            const int tok = m0 + wm*64 + mi*16 + fq*4 + j;
            #pragma unroll
            for (int ni=0;ni<6;++ni) {
                const int n = wn*96 + ni*16 + fr;
                out[(size_t)tok*DMODEL + n] = acc[mi][ni][j];
            }
        }
    }
}

// ---------------------------------------------------------------------------
extern "C" void kernel_launch(void* const* d_in, const int* in_sizes, int n_in,
                              void* d_out, int out_size, void* d_ws, size_t ws_size,
                              hipStream_t stream)
{
    const float* u      = (const float*)d_in[0];
    const float* t      = (const float*)d_in[1];
    const float* Win    = (const float*)d_in[2];
    const float* Wtin   = (const float*)d_in[3];
    const float* conv_w = (const float*)d_in[4];
    const float* conv_b = (const float*)d_in[5];
    const float* dt_b   = (const float*)d_in[6];
    const float* A_log  = (const float*)d_in[7];
    const float* Dv     = (const float*)d_in[8];
    const float* ln_g   = (const float*)d_in[9];
    const float* ln_bt  = (const float*)d_in[10];
    const float* W_out  = (const float*)d_in[11];
    float* out = (float*)d_out;

    char* p = (char*)d_ws;
    bf16* z_bf     = (bf16*)p;  p += (size_t)NTOK*DINNER*2;   // 50.3 MB
    bf16* xbc_pre  = (bf16*)p;  p += (size_t)NTOK*CONVD*2;    // 54.5 MB (reused as kv partials after conv)
    bf16* xbc_post = (bf16*)p;  p += (size_t)NTOK*CONVD*2;    // 54.5 MB
    float* cq_pre  = (float*)p; p += (size_t)NTOK*DST*4;      //  4.2 MB
    float* cq_post = (float*)p; p += (size_t)NTOK*DST*4;      //  4.2 MB
    float* dA      = (float*)p; p += (size_t)NTOK*NH*4;       //  8.4 MB
    bf16* yz       = (bf16*)p;  p += (size_t)NTOK*DINNER*2;   // 50.3 MB
    float* kv      = (float*)p; p += (size_t)BN*NH*DST*HD*4;  // 98 KB
    bf16* Win_bf   = (bf16*)p;  p += (size_t)832*DMODEL*2;    // 320 KB
    bf16* Wout_bf  = (bf16*)p;  p += (size_t)DMODEL*DINNER*2; // 148 KB
    float* wtr     = (float*)p; p += (size_t)9*420*4;         // 15.1 KB

    float* kv_part = (float*)xbc_pre;   // 6.3 MB, xbc_pre dead after k_conv416

    k_prep<<<624, 256, 0, stream>>>(Win, W_out, conv_w, Win_bf, Wout_bf, wtr);
    k_proj_mfma<<<512, 256, 0, stream>>>(u, Win_bf, dt_b, A_log, z_bf, xbc_pre, dA);
    k_tproj<<<NTOK/16, 256, 0, stream>>>(t, Wtin, cq_pre);
    k_conv416<<<NTOK/8, 416, 0, stream>>>(xbc_pre, wtr, conv_b, xbc_post);
    k_conv16<<<NTOK*16/256, 256, 0, stream>>>(cq_pre, conv_w, conv_b, cq_post);
    k_kv<<<dim3(KVCHUNKS, BN), 512, 0, stream>>>(xbc_post, dA, kv_part);
    k_kvred<<<BN*6144/256, 256, 0, stream>>>(kv_part, kv);
    k_ynorm<<<NTOK/16, 256, 0, stream>>>(xbc_post, cq_post, z_bf, kv,
                                         Dv, ln_g, ln_bt, yz);
    k_out_mfma<<<512, 256, 0, stream>>>(yz, Wout_bf, out);
}

// Round 8
// 313.358 us; speedup vs baseline: 3.0612x; 1.0152x over previous
//
#include <hip/hip_runtime.h>
#include <hip/hip_bf16.h>
#include <math.h>

// Mamba2 fused block, round 8: k_proj_mfma rebuilt on 32x32x16 MFMA —
// A in registers (no LDS), B 64-ch tiles double-buffered with load-early/
// write-late staging, one barrier per tile, 2x FLOP per LDS byte.
// Other kernels unchanged from round 7.

#define BN 4
#define HH 128
#define WWID 128
#define LTOK (HH*WWID)          // 16384
#define NTOK (BN*LTOK)          // 65536
#define DMODEL 192
#define DINNER 384
#define NH 32
#define HD 12
#define DST 16
#define CONVD 416               // D_INNER + 2*16
#define KVCHUNKS 64             // L-chunks per batch for k_kv
#define PM 256                  // k_proj tokens per block
#define PBN 64                  // k_proj B-tile channels
#define BSTR 200                // k_proj B row stride in shorts (400B, 16B-aligned)

typedef __hip_bfloat16 bf16;
typedef unsigned int uint32;
typedef unsigned short ushort16;
typedef __attribute__((ext_vector_type(8))) short bf16x8;
typedef __attribute__((ext_vector_type(4))) float f32x4;
typedef __attribute__((ext_vector_type(16))) float f32x16;

__device__ __forceinline__ float bflo(uint32 v){ return __uint_as_float((v & 0xffffu) << 16); }
__device__ __forceinline__ float bfhi(uint32 v){ return __uint_as_float(v & 0xffff0000u); }
__device__ __forceinline__ ushort16 f2bf(float f){
    __hip_bfloat16 h = __float2bfloat16(f);
    return *reinterpret_cast<const ushort16*>(&h);
}
__device__ __forceinline__ float softplusf(float x){
    return (x > 20.f) ? x : log1pf(expf(x));
}
__device__ __forceinline__ float siluf(float x){
    return x / (1.f + expf(-x));
}

union BFPK { short s[8]; bf16x8 v; };

// ---------------------------------------------------------------------------
// k_prep: convert Win (832x192), Wout (192x384) to bf16; transpose conv
// weights to wtr[9][420] f32 (tap-major, padded).
// ---------------------------------------------------------------------------
__global__ __launch_bounds__(256) void k_prep(
    const float* __restrict__ Win, const float* __restrict__ Wout,
    const float* __restrict__ cw,
    bf16* __restrict__ Winbf, bf16* __restrict__ Woutbf, float* __restrict__ wtr)
{
    const int i = blockIdx.x*256 + threadIdx.x;
    if (i < 832*DMODEL)   Winbf[i]  = __float2bfloat16(Win[i]);
    if (i < DMODEL*DINNER) Woutbf[i] = __float2bfloat16(Wout[i]);
    if (i < CONVD*9) { const int c = i/9, k = i - c*9; wtr[k*420 + c] = cw[i]; }
}

// ---------------------------------------------------------------------------
// k_proj_mfma: zxbcdt = u @ Win^T via 32x32x16 bf16 MFMA.
// Block = 256 tokens (8 waves x 32 tokens), grid 256 (1 block/CU).
// A: global->reg f32->bf16, a[12] frags (row=lane&31, k=ks*16+(lane>>5)*8+i).
// B: 13 tiles of 64 ch x 192 k, LDS double-buffered [2][64][200] (51.2 KB),
// load-early (regs, one tile ahead) / ds_write-late, 1 barrier/tile.
// Per tile per wave: 24 ds_read_b128 : 24 MFMA (32K FLOP each) — balanced.
// C/D: col=lane&31 (channel), row=(reg&3)+8*(reg>>2)+4*(lane>>5) (token).
// ---------------------------------------------------------------------------
__global__ __launch_bounds__(512) void k_proj_mfma(
    const float* __restrict__ u, const bf16* __restrict__ Wbf,
    const float* __restrict__ dt_b, const float* __restrict__ A_log,
    bf16* __restrict__ z_bf, bf16* __restrict__ xbc_pre, float* __restrict__ dA)
{
    __shared__ __align__(16) short S[2][PBN*BSTR];   // 2 x 25.6 KB

    const int tid = threadIdx.x;
    const int m0 = blockIdx.x * PM;
    const int wid = tid >> 6, lane = tid & 63;
    const int fr = lane & 31;      // channel col / token row within 32
    const int hi = lane >> 5;      // k half

    // ---- A fragments: direct global->reg, f32->bf16 ----
    bf16x8 a[12];
    {
        const float* arow = u + (size_t)(m0 + wid*32 + fr)*DMODEL;
        #pragma unroll
        for (int ks=0;ks<12;++ks) {
            const float4 a0 = *(const float4*)(arow + ks*16 + hi*8);
            const float4 a1 = *(const float4*)(arow + ks*16 + hi*8 + 4);
            BFPK pk;
            pk.s[0]=(short)f2bf(a0.x); pk.s[1]=(short)f2bf(a0.y);
            pk.s[2]=(short)f2bf(a0.z); pk.s[3]=(short)f2bf(a0.w);
            pk.s[4]=(short)f2bf(a1.x); pk.s[5]=(short)f2bf(a1.y);
            pk.s[6]=(short)f2bf(a1.z); pk.s[7]=(short)f2bf(a1.w);
            a[ks] = pk.v;
        }
    }

    // ---- B staging: thread -> (row = tid>>3 of 64, seg = tid&7 of 8x24sh) ----
    const int srow = tid >> 3;
    const int sseg = tid & 7;
    uint4 r0, r1, r2;
    auto LOADB = [&](int nt) {
        const short* g = (const short*)Wbf + (size_t)(nt*PBN + srow)*DMODEL + sseg*24;
        r0 = *(const uint4*)g;
        r1 = *(const uint4*)(g + 8);
        r2 = *(const uint4*)(g + 16);
    };
    auto WRITEB = [&](int buf) {
        short* d = &S[buf][srow*BSTR + sseg*24];
        *(uint4*)d        = r0;
        *(uint4*)(d + 8)  = r1;
        *(uint4*)(d + 16) = r2;
    };

    LOADB(0); WRITEB(0);
    LOADB(1);                      // in flight across tile 0's compute
    __syncthreads();

    for (int nt = 0; nt < 13; ++nt) {
        const int cur = nt & 1;

        f32x16 acc0, acc1;
        #pragma unroll
        for (int i=0;i<16;++i) { acc0[i]=0.f; acc1[i]=0.f; }

        const short* Sb = &S[cur][0];
        #pragma unroll
        for (int ks=0;ks<12;++ks) {
            const bf16x8 b0 = *(const bf16x8*)&Sb[(fr     )*BSTR + ks*16 + hi*8];
            const bf16x8 b1 = *(const bf16x8*)&Sb[(32 + fr)*BSTR + ks*16 + hi*8];
            acc0 = __builtin_amdgcn_mfma_f32_32x32x16_bf16(a[ks], b0, acc0, 0, 0, 0);
            acc1 = __builtin_amdgcn_mfma_f32_32x32x16_bf16(a[ks], b1, acc1, 0, 0, 0);
        }

        // ---- epilogue (region uniform per (nt,ni): boundaries 384/800 are x32) ----
        #pragma unroll
        for (int ni=0;ni<2;++ni) {
            const f32x16& ac = ni ? acc1 : acc0;
            const int n0 = nt*64 + ni*32;
            const int n  = n0 + fr;
            if (n0 < DINNER) {
                #pragma unroll
                for (int r=0;r<16;++r) {
                    const int tok = m0 + wid*32 + (r&3) + 8*(r>>2) + 4*hi;
                    z_bf[(size_t)tok*DINNER + n] = __float2bfloat16(ac[r]);
                }
            } else if (n0 < 800) {
                #pragma unroll
                for (int r=0;r<16;++r) {
                    const int tok = m0 + wid*32 + (r&3) + 8*(r>>2) + 4*hi;
                    xbc_pre[(size_t)tok*CONVD + (n - DINNER)] = __float2bfloat16(ac[r]);
                }
            } else {
                const float db = dt_b[fr];
                const float al = expf(A_log[fr]);
                #pragma unroll
                for (int r=0;r<16;++r) {
                    const int tok = m0 + wid*32 + (r&3) + 8*(r>>2) + 4*hi;
                    const float dt = softplusf(ac[r] + db);
                    dA[(size_t)tok*NH + fr] = dt * al;
                }
            }
        }

        if (nt < 12) {
            WRITEB(cur ^ 1);               // tile nt+1 (loaded last iter)
            if (nt < 11) LOADB(nt + 2);    // in flight across next compute
        }
        __syncthreads();
    }
}

// ---------------------------------------------------------------------------
// k_tproj: cq_pre[tok][n] = t[tok] . Wtin[784+n], n=0..15. 16 tokens/block.
// ---------------------------------------------------------------------------
__global__ __launch_bounds__(256) void k_tproj(
    const float* __restrict__ t, const float* __restrict__ Wtin, float* __restrict__ cq_pre)
{
    __shared__ float ts[16][196];
    __shared__ float ws[16][196];
    const int tid = threadIdx.x;
    const int tok0 = blockIdx.x * 16;
    #pragma unroll
    for (int i = 0; i < 3; ++i) {
        const int flat = tid + 256*i;          // 0..767
        const int row = flat / 48, c = (flat % 48)*4;
        *(float4*)&ts[row][c] = *(const float4*)(t    + (size_t)(tok0+row)*DMODEL + c);
        *(float4*)&ws[row][c] = *(const float4*)(Wtin + (size_t)(784+row)*DMODEL + c);
    }
    __syncthreads();
    const int tt = tid >> 4, n = tid & 15;
    float s0=0.f,s1=0.f,s2=0.f,s3=0.f;
    #pragma unroll 4
    for (int k = 0; k < DMODEL; k += 4) {
        s0 = fmaf(ts[tt][k+0], ws[n][k+0], s0);
        s1 = fmaf(ts[tt][k+1], ws[n][k+1], s1);
        s2 = fmaf(ts[tt][k+2], ws[n][k+2], s2);
        s3 = fmaf(ts[tt][k+3], ws[n][k+3], s3);
    }
    cq_pre[(size_t)(tok0+tt)*DST + n] = (s0+s1)+(s2+s3);
}

// ---------------------------------------------------------------------------
// k_conv416: depthwise 3x3 SAME conv + bias + SiLU, 8 channels/thread.
// ---------------------------------------------------------------------------
__global__ __launch_bounds__(416) void k_conv416(
    const bf16* __restrict__ in, const float* __restrict__ wtr, const float* __restrict__ cb,
    bf16* __restrict__ out)
{
    __shared__ float ws[9*420];    // 15.1 KB
    __shared__ float bs[416];
    const int tid = threadIdx.x;
    for (int i = tid; i < 9*420; i += 416) ws[i] = wtr[i];
    if (tid < 416) bs[tid] = cb[tid];
    __syncthreads();

    const int pl  = tid / 52;
    const int grp = tid - pl*52;
    const int c0  = grp*8;
    const int pix = blockIdx.x*8 + pl;
    const int hw  = pix & (LTOK-1);
    const int h = hw >> 7, w = hw & 127;
    const int bb = pix >> 14;

    float acc[8];
    {
        const float4 b0 = *(const float4*)&bs[c0];
        const float4 b1 = *(const float4*)&bs[c0+4];
        acc[0]=b0.x; acc[1]=b0.y; acc[2]=b0.z; acc[3]=b0.w;
        acc[4]=b1.x; acc[5]=b1.y; acc[6]=b1.z; acc[7]=b1.w;
    }

    #pragma unroll
    for (int dh=-1; dh<=1; ++dh) {
        const int hh = h + dh;
        if ((unsigned)hh >= (unsigned)HH) continue;
        #pragma unroll
        for (int dw=-1; dw<=1; ++dw) {
            const int w2 = w + dw;
            if ((unsigned)w2 >= (unsigned)WWID) continue;
            const int wi = (dh+1)*3 + (dw+1);
            const size_t off = ((size_t)((bb<<14) + (hh<<7) + w2))*CONVD + c0;
            const uint4 v = *(const uint4*)((const ushort16*)in + off);
            const float4 w0 = *(const float4*)&ws[wi*420 + c0];
            const float4 w1 = *(const float4*)&ws[wi*420 + c0 + 4];
            acc[0] = fmaf(bflo(v.x), w0.x, acc[0]);
            acc[1] = fmaf(bfhi(v.x), w0.y, acc[1]);
            acc[2] = fmaf(bflo(v.y), w0.z, acc[2]);
            acc[3] = fmaf(bfhi(v.y), w0.w, acc[3]);
            acc[4] = fmaf(bflo(v.z), w1.x, acc[4]);
            acc[5] = fmaf(bfhi(v.z), w1.y, acc[5]);
            acc[6] = fmaf(bflo(v.w), w1.z, acc[6]);
            acc[7] = fmaf(bfhi(v.w), w1.w, acc[7]);
        }
    }

    uint4 o;
    o.x = ((uint32)f2bf(siluf(acc[1])) << 16) | (uint32)f2bf(siluf(acc[0]));
    o.y = ((uint32)f2bf(siluf(acc[3])) << 16) | (uint32)f2bf(siluf(acc[2]));
    o.z = ((uint32)f2bf(siluf(acc[5])) << 16) | (uint32)f2bf(siluf(acc[4]));
    o.w = ((uint32)f2bf(siluf(acc[7])) << 16) | (uint32)f2bf(siluf(acc[6]));
    *(uint4*)((ushort16*)out + (size_t)pix*CONVD + c0) = o;
}

// ---------------------------------------------------------------------------
// k_conv16: same conv for the 16 Cq channels (conv channels 400..415), f32.
// ---------------------------------------------------------------------------
__global__ __launch_bounds__(256) void k_conv16(
    const float* __restrict__ in, const float* __restrict__ cw, const float* __restrict__ cb,
    float* __restrict__ out)
{
    const int idx = blockIdx.x*256 + threadIdx.x;   // NTOK*16
    const int cc = idx & 15;
    const int pix = idx >> 4;
    const int hw = pix & (LTOK-1);
    const int h = hw >> 7, w = hw & 127;
    const int bb = pix >> 14;
    const int c = 400 + cc;

    float wg[9];
    #pragma unroll
    for (int k=0;k<9;++k) wg[k] = cw[c*9+k];
    float a = cb[c];
    #pragma unroll
    for (int dh=-1; dh<=1; ++dh) {
        const int hh = h + dh;
        if ((unsigned)hh >= (unsigned)HH) continue;
        #pragma unroll
        for (int dw=-1; dw<=1; ++dw) {
            const int w2 = w + dw;
            if ((unsigned)w2 >= (unsigned)WWID) continue;
            a = fmaf(in[((size_t)((bb<<14)+(hh<<7)+w2))*16 + cc], wg[(dh+1)*3 + (dw+1)], a);
        }
    }
    out[(size_t)pix*16 + cc] = siluf(a);
}

// ---------------------------------------------------------------------------
// k_kv: partial KV per (batch, 256-token chunk). 16 tokens staged per barrier
// (raw bf16 copy), dA scaling folded into compute. No atomics.
// ---------------------------------------------------------------------------
__global__ __launch_bounds__(512) void k_kv(
    const bf16* __restrict__ xbc_post, const float* __restrict__ dA,
    float* __restrict__ partial)
{
    __shared__ short vsb[16][408];   // 16 tokens x 400 ch (bf16 raw), +8 pad
    __shared__ float das[16][32];
    const int tid = threadIdx.x;
    const int b = blockIdx.y;
    const int n = tid & 15;
    const int g = tid >> 4;          // head

    float acc[12];
    #pragma unroll
    for (int j=0;j<12;++j) acc[j]=0.f;

    const int l0base = b*LTOK + blockIdx.x*256;

    for (int it = 0; it < 16; ++it) {
        const int l0 = l0base + it*16;
        for (int i = tid; i < 16*200; i += 512) {
            const int tok = i / 200;
            const int c2 = i - tok*200;
            const uint32 v = *(const uint32*)((const ushort16*)xbc_post
                                + (size_t)(l0+tok)*CONVD + c2*2);
            *(uint32*)&vsb[tok][c2*2] = v;
        }
        {
            const int tok = tid >> 5, h = tid & 31;
            das[tok][h] = dA[(size_t)(l0+tok)*NH + h];
        }
        __syncthreads();

        #pragma unroll
        for (int tok = 0; tok < 16; ++tok) {
            const uint32 bkraw = (uint32)(ushort16)vsb[tok][DINNER + n];
            const float s = __uint_as_float(bkraw << 16) * das[tok][g];
            const uint32* vp = (const uint32*)&vsb[tok][g*12];
            const uint32 w0 = vp[0], w1 = vp[1], w2 = vp[2];
            acc[0]  = fmaf(s, bflo(w0), acc[0]);
            acc[1]  = fmaf(s, bfhi(w0), acc[1]);
            acc[2]  = fmaf(s, bflo(w1), acc[2]);
            acc[3]  = fmaf(s, bfhi(w1), acc[3]);
            acc[4]  = fmaf(s, bflo(w2), acc[4]);
            acc[5]  = fmaf(s, bfhi(w2), acc[5]);
            const uint32* vq = (const uint32*)&vsb[tok][g*12 + 6];
            const uint32 w3 = vq[0], w4 = vq[1], w5 = vq[2];
            acc[6]  = fmaf(s, bflo(w3), acc[6]);
            acc[7]  = fmaf(s, bfhi(w3), acc[7]);
            acc[8]  = fmaf(s, bflo(w4), acc[8]);
            acc[9]  = fmaf(s, bfhi(w4), acc[9]);
            acc[10] = fmaf(s, bflo(w5), acc[10]);
            acc[11] = fmaf(s, bfhi(w5), acc[11]);
        }
        __syncthreads();
    }

    float* dst = partial + ((size_t)(b*KVCHUNKS + blockIdx.x))*6144 + (size_t)tid*12;
    #pragma unroll
    for (int j4=0;j4<3;++j4)
        *(float4*)(dst + j4*4) = make_float4(acc[j4*4], acc[j4*4+1], acc[j4*4+2], acc[j4*4+3]);
}

// ---------------------------------------------------------------------------
// k_kvred: kv[b][flat] = sum_{c<64} partial[b*64+c][flat].
// ---------------------------------------------------------------------------
__global__ __launch_bounds__(256) void k_kvred(
    const float* __restrict__ partial, float* __restrict__ kv)
{
    const int idx = blockIdx.x*256 + threadIdx.x;   // 4*6144
    const int b = idx / 6144;
    const int flat = idx - b*6144;
    const float* p = partial + (size_t)(b*KVCHUNKS)*6144 + flat;
    float s = 0.f;
    #pragma unroll 4
    for (int c = 0; c < KVCHUNKS; ++c) s += p[(size_t)c*6144];
    kv[idx] = s;
}

// ---------------------------------------------------------------------------
// k_ynorm: y = Cq @ KV + V*D, LayerNorm(384), gate by z -> yz (bf16).
// ---------------------------------------------------------------------------
__global__ __launch_bounds__(256) void k_ynorm(
    const bf16* __restrict__ xbc_post, const float* __restrict__ cq_post,
    const bf16* __restrict__ z_bf, const float* __restrict__ kv,
    const float* __restrict__ Dv, const float* __restrict__ ln_g, const float* __restrict__ ln_b,
    bf16* __restrict__ yz)
{
    __shared__ float kvs[NH*DST*HD];   // 6144, layout [n][hd]
    __shared__ float ys[16][386];
    __shared__ float cqs[16][16];
    const int tid = threadIdx.x;
    const int token0 = blockIdx.x * 16;
    const int b = token0 >> 14;

    for (int i = tid; i < NH*DST*HD; i += 256) {
        const int n = i / DINNER;
        const int hd = i - n*DINNER;
        const int h = hd / HD;
        const int d = hd - h*HD;
        kvs[i] = kv[((size_t)(b*NH + h)*DST + n)*HD + d];
    }
    {
        const int tt = tid >> 4, n2 = tid & 15;
        cqs[tt][n2] = cq_post[(size_t)(token0+tt)*DST + n2];
    }
    __syncthreads();

    #pragma unroll
    for (int jj=0; jj<12; ++jj) {
        const int flat = jj*256 + tid;     // 0..3071 (pairs)
        const int tt = flat / 192;
        const int p  = flat - tt*192;
        const int hd = p*2;
        const int h = hd / HD;
        const int l = token0 + tt;
        const uint32 v = *(const uint32*)((const ushort16*)xbc_post + (size_t)l*CONVD + hd);
        const float dv = Dv[h];
        float a0 = bflo(v) * dv;
        float a1 = bfhi(v) * dv;
        #pragma unroll
        for (int n=0;n<16;++n) {
            const float c = cqs[tt][n];
            const float2 kk = *(const float2*)&kvs[n*DINNER + hd];
            a0 = fmaf(c, kk.x, a0);
            a1 = fmaf(c, kk.y, a1);
        }
        *(float2*)&ys[tt][hd] = make_float2(a0, a1);
    }
    __syncthreads();

    const int wave = tid >> 6, lane = tid & 63;
    #pragma unroll
    for (int i=0;i<4;++i) {
        const int tt = wave*4 + i;
        const int l = token0 + tt;
        float v[6]; float s=0.f, s2=0.f;
        #pragma unroll
        for (int k=0;k<6;++k){ const float x = ys[tt][k*64+lane]; v[k]=x; s+=x; s2=fmaf(x,x,s2); }
        #pragma unroll
        for (int off=32; off>0; off>>=1){ s += __shfl_xor(s,off,64); s2 += __shfl_xor(s2,off,64); }
        const float mu = s*(1.f/384.f);
        const float var = s2*(1.f/384.f) - mu*mu;
        const float rs = rsqrtf(var + 1e-5f);
        #pragma unroll
        for (int k=0;k<6;++k){
            const int idx = k*64+lane;
            const float yn = (v[k]-mu)*rs*ln_g[idx] + ln_b[idx];
            const uint32 zb = (uint32)(*((const ushort16*)z_bf + (size_t)l*DINNER + idx));
            const float zv = __uint_as_float(zb << 16);
            yz[(size_t)l*DINNER + idx] = __float2bfloat16(yn*zv);
        }
    }
}

// ---------------------------------------------------------------------------
// k_out_mfma: out = yz @ Wout^T via MFMA. (unchanged r2)
// ---------------------------------------------------------------------------
__global__ __launch_bounds__(256) void k_out_mfma(
    const bf16* __restrict__ yz, const bf16* __restrict__ Wbf, float* __restrict__ out)
{
    __shared__ __align__(16) short As[2][128*40];
    __shared__ __align__(16) short Bs[2][192*40];

    const int tid = threadIdx.x;
    const int m0 = blockIdx.x * 128;
    const int wid = tid >> 6, lane = tid & 63;
    const int wm = wid >> 1, wn = wid & 1;
    const int fr = lane & 15, fq = lane >> 4;

    const int arow = tid >> 1, ahalf = tid & 1;
    auto stageA = [&](int ks, int buf) {
        const short* g = (const short*)yz + (size_t)(m0 + arow)*DINNER + ks*32 + ahalf*16;
        const uint4 v0 = *(const uint4*)g;
        const uint4 v1 = *(const uint4*)(g + 8);
        short* d = &As[buf][arow*40 + ahalf*16];
        *(uint4*)d = v0;
        *(uint4*)(d + 8) = v1;
    };
    auto stageB = [&](int ks, int buf) {
        #pragma unroll
        for (int i = 0; i < 3; ++i) {
            const int flat = tid + 256*i;      // 0..767
            const int row = flat >> 2, q = flat & 3;
            const uint4 v = *(const uint4*)((const short*)Wbf + (size_t)row*DINNER + ks*32 + q*8);
            *(uint4*)&Bs[buf][row*40 + q*8] = v;
        }
    };

    f32x4 acc[4][6];
    #pragma unroll
    for (int mi=0;mi<4;++mi)
        #pragma unroll
        for (int ni=0;ni<6;++ni) acc[mi][ni] = (f32x4){0.f,0.f,0.f,0.f};

    stageA(0, 0); stageB(0, 0);
    __syncthreads();

    const int aoff = (wm*64 + fr)*40 + fq*8;
    const int boff = (wn*96 + fr)*40 + fq*8;

    #pragma unroll
    for (int ks = 0; ks < 12; ++ks) {
        const int cur = ks & 1;
        if (ks < 11) { stageA(ks+1, cur^1); stageB(ks+1, cur^1); }
        bf16x8 a[4], b[6];
        #pragma unroll
        for (int mi=0;mi<4;++mi) a[mi] = *(const bf16x8*)(&As[cur][aoff + mi*640]);
        #pragma unroll
        for (int ni=0;ni<6;++ni) b[ni] = *(const bf16x8*)(&Bs[cur][boff + ni*640]);
        #pragma unroll
        for (int mi=0;mi<4;++mi)
            #pragma unroll
            for (int ni=0;ni<6;++ni)
                acc[mi][ni] = __builtin_amdgcn_mfma_f32_16x16x32_bf16(a[mi], b[ni], acc[mi][ni], 0, 0, 0);
        __syncthreads();
    }

    #pragma unroll
    for (int mi=0;mi<4;++mi) {
        #pragma unroll
        for (int j=0;j<4;++j) {
            const int tok = m0 + wm*64 + mi*16 + fq*4 + j;
            #pragma unroll
            for (int ni=0;ni<6;++ni) {
                const int n = wn*96 + ni*16 + fr;
                out[(size_t)tok*DMODEL + n] = acc[mi][ni][j];
            }
        }
    }
}

// ---------------------------------------------------------------------------
extern "C" void kernel_launch(void* const* d_in, const int* in_sizes, int n_in,
                              void* d_out, int out_size, void* d_ws, size_t ws_size,
                              hipStream_t stream)
{
    const float* u      = (const float*)d_in[0];
    const float* t      = (const float*)d_in[1];
    const float* Win    = (const float*)d_in[2];
    const float* Wtin   = (const float*)d_in[3];
    const float* conv_w = (const float*)d_in[4];
    const float* conv_b = (const float*)d_in[5];
    const float* dt_b   = (const float*)d_in[6];
    const float* A_log  = (const float*)d_in[7];
    const float* Dv     = (const float*)d_in[8];
    const float* ln_g   = (const float*)d_in[9];
    const float* ln_bt  = (const float*)d_in[10];
    const float* W_out  = (const float*)d_in[11];
    float* out = (float*)d_out;

    char* p = (char*)d_ws;
    bf16* z_bf     = (bf16*)p;  p += (size_t)NTOK*DINNER*2;   // 50.3 MB
    bf16* xbc_pre  = (bf16*)p;  p += (size_t)NTOK*CONVD*2;    // 54.5 MB (reused as kv partials after conv)
    bf16* xbc_post = (bf16*)p;  p += (size_t)NTOK*CONVD*2;    // 54.5 MB
    float* cq_pre  = (float*)p; p += (size_t)NTOK*DST*4;      //  4.2 MB
    float* cq_post = (float*)p; p += (size_t)NTOK*DST*4;      //  4.2 MB
    float* dA      = (float*)p; p += (size_t)NTOK*NH*4;       //  8.4 MB
    bf16* yz       = (bf16*)p;  p += (size_t)NTOK*DINNER*2;   // 50.3 MB
    float* kv      = (float*)p; p += (size_t)BN*NH*DST*HD*4;  // 98 KB
    bf16* Win_bf   = (bf16*)p;  p += (size_t)832*DMODEL*2;    // 320 KB
    bf16* Wout_bf  = (bf16*)p;  p += (size_t)DMODEL*DINNER*2; // 148 KB
    float* wtr     = (float*)p; p += (size_t)9*420*4;         // 15.1 KB

    float* kv_part = (float*)xbc_pre;   // 6.3 MB, xbc_pre dead after k_conv416

    k_prep<<<624, 256, 0, stream>>>(Win, W_out, conv_w, Win_bf, Wout_bf, wtr);
    k_proj_mfma<<<NTOK/PM, 512, 0, stream>>>(u, Win_bf, dt_b, A_log, z_bf, xbc_pre, dA);
    k_tproj<<<NTOK/16, 256, 0, stream>>>(t, Wtin, cq_pre);
    k_conv416<<<NTOK/8, 416, 0, stream>>>(xbc_pre, wtr, conv_b, xbc_post);
    k_conv16<<<NTOK*16/256, 256, 0, stream>>>(cq_pre, conv_w, conv_b, cq_post);
    k_kv<<<dim3(KVCHUNKS, BN), 512, 0, stream>>>(xbc_post, dA, kv_part);
    k_kvred<<<BN*6144/256, 256, 0, stream>>>(kv_part, kv);
    k_ynorm<<<NTOK/16, 256, 0, stream>>>(xbc_post, cq_post, z_bf, kv,
                                         Dv, ln_g, ln_bt, yz);
    k_out_mfma<<<512, 256, 0, stream>>>(yz, Wout_bf, out);
}